// Round 13
// baseline (187.054 us; speedup 1.0000x reference)
//
#include <hip/hip_runtime.h>
#include <hip/hip_bf16.h>

#define NB 2
#define LL 2048
#define EE 1024
#define HH 16
#define HDD 64
#define FFD 4096

typedef unsigned short ushort_t;
typedef __attribute__((ext_vector_type(8))) short short8;
typedef __attribute__((ext_vector_type(4))) float f32x4;

constexpr float LN_EPS = 1e-5f;
constexpr float QSCALE = 0.03125f * 1.44269504088896340736f;  // 1/32 * log2(e)

__device__ inline ushort_t f2bf(float f) {
    union { __hip_bfloat16 b; ushort_t u; } v;
    v.b = __float2bfloat16(f);
    return v.u;
}
__device__ inline float bf2f(unsigned us) {
    union { unsigned u; float f; } v; v.u = us << 16; return v.f;
}
// pack trunc-bf16(lo) | trunc-bf16(hi)<<16 in ONE v_perm_b32
__device__ inline unsigned pk_hi16(float lo, float hi) {
    const unsigned sel = 0x07060302u;
    unsigned r;
    asm("v_perm_b32 %0, %1, %2, %3" : "=v"(r) : "v"(hi), "v"(lo), "s"(sel));
    return r;
}

__device__ inline void gload16(const void* g, void* lds) {
    __builtin_amdgcn_global_load_lds(
        (const __attribute__((address_space(1))) void*)g,
        (__attribute__((address_space(3))) void*)lds, 16, 0, 0);
}

// ---------------------------------------------------------------------------
// K convert: [N,L,H,D] f32 -> [N,H,L,D] bf16.
// ---------------------------------------------------------------------------
__global__ __launch_bounds__(256) void k_cvt(
    const float* __restrict__ in, ushort_t* __restrict__ out)
{
    const int t = threadIdx.x;
    const int g = blockIdx.x * 32 + (t >> 3);          // (n*H+h)*L + l
    const int n = g >> 15, h = (g >> 11) & 15, l2 = g & 2047;
    const int d0 = (t & 7) * 8;
    const float* src = in + ((size_t)(n * LL + l2) * HH + h) * HDD + d0;
    const float4 a = *(const float4*)src;
    const float4 b = *(const float4*)(src + 4);
    uint4 pk;
    pk.x = f2bf(a.x) | ((unsigned)f2bf(a.y) << 16);
    pk.y = f2bf(a.z) | ((unsigned)f2bf(a.w) << 16);
    pk.z = f2bf(b.x) | ((unsigned)f2bf(b.y) << 16);
    pk.w = f2bf(b.z) | ((unsigned)f2bf(b.w) << 16);
    *(uint4*)(out + (size_t)g * HDD + d0) = pk;
}

// ---------------------------------------------------------------------------
// V convert+transpose: [N,L,H,D] f32 -> [N,H,D,L] bf16, kv-permuted columns:
//   phys(c') = ((c'>>5)*2 + ((c'>>2)&1))*16 + ((c'>>3)&3)*4 + (c'&3)
// ---------------------------------------------------------------------------
__global__ __launch_bounds__(256) void v_cvt_t(
    const float* __restrict__ in, ushort_t* __restrict__ out)
{
    __shared__ float T[64][68];
    const int lb = blockIdx.x, h = blockIdx.y, n = blockIdx.z;
    const int t = threadIdx.x;
    const int l0 = lb * 64;
    {
        const int r = t >> 2, c0 = (t & 3) * 16;
        const float* src = in + ((size_t)(n * LL + l0 + r) * HH + h) * HDD + c0;
#pragma unroll
        for (int i = 0; i < 4; ++i)
            *(float4*)&T[r][c0 + 4 * i] = *(const float4*)(src + 4 * i);
    }
    __syncthreads();
    {
        const int d = t >> 2, tq = t & 3;
        unsigned u[8];
#pragma unroll
        for (int k = 0; k < 8; ++k) {
            const int c0 = tq * 16 + 2 * k, c1 = c0 + 1;
            const int p0 = (((c0 >> 5) * 2 + ((c0 >> 2) & 1)) << 4) +
                           (((c0 >> 3) & 3) << 2) + (c0 & 3);
            const int p1 = (((c1 >> 5) * 2 + ((c1 >> 2) & 1)) << 4) +
                           (((c1 >> 3) & 3) << 2) + (c1 & 3);
            u[k] = f2bf(T[p0][d]) | ((unsigned)f2bf(T[p1][d]) << 16);
        }
        ushort_t* dst = out + ((size_t)(n * HH + h) * HDD + d) * LL + l0 + tq * 16;
        uint4 q0; q0.x = u[0]; q0.y = u[1]; q0.z = u[2]; q0.w = u[3];
        uint4 q1; q1.x = u[4]; q1.y = u[5]; q1.z = u[6]; q1.w = u[7];
        *(uint4*)(dst)     = q0;
        *(uint4*)(dst + 8) = q1;
    }
}

// ---------------------------------------------------------------------------
// MFMA flash attention, software-pipelined: QK(kt+1) issued BEFORE
// softmax(kt)+PV(kt) so the matrix pipe drains under the VALU softmax.
// K 3-deep / V 2-deep LDS (40KB), counted vmcnt(4) keeps exactly the newest
// {K(kt+3),V(kt+2)} in flight. Swapped QK^T, in-register P (v_perm pack),
// native v_exp, ones-column row-sum, XCD-bijective mapping.
// Block = (n,h,64 q rows), 4 waves x 16 q rows, grid 1024.
// ---------------------------------------------------------------------------
__global__ __launch_bounds__(256) void attn_mfma(
    const float* __restrict__ Qf,     // [N,L,H,D] f32 (raw query)
    const ushort_t* __restrict__ Kh,  // [N,H,L,D] bf16
    const ushort_t* __restrict__ Vt,  // [N,H,D,L] bf16 kv-permuted
    ushort_t* __restrict__ O)         // [N,L,E] bf16
{
    const int s = blockIdx.x;          // grid = 1024
    const int xcd = s & 7, seq = s >> 3;
    const int qb = seq & 31, tt = seq >> 5;
    const int h = ((tt & 1) << 3) | xcd;
    const int n = tt >> 1;

    const int t = threadIdx.x, w = t >> 6, l = t & 63;
    const int lr = l & 15, lg = l >> 4;

    __shared__ __align__(16) ushort_t Kl[3][64 * 64];  // 24 KB
    __shared__ __align__(16) ushort_t Vl[2][64 * 64];  // 16 KB

    const size_t hbase = ((size_t)n * HH + h) * LL * HDD;
    const size_t vbase = ((size_t)n * HH + h) * HDD * LL;
    const int q0 = qb * 64 + w * 16;

    // Q fragments (B-operand), converted+scaled in-kernel
    short8 bq[2];
#pragma unroll
    for (int ks = 0; ks < 2; ++ks) {
        const float* qsrc = Qf + ((size_t)(n * LL + q0 + lr) * HH + h) * HDD
                               + ks * 32 + lg * 8;
        const float4 a = *(const float4*)qsrc;
        const float4 b = *(const float4*)(qsrc + 4);
        union { short8 s8; unsigned u[4]; } pk;
        pk.u[0] = f2bf(a.x * QSCALE) | ((unsigned)f2bf(a.y * QSCALE) << 16);
        pk.u[1] = f2bf(a.z * QSCALE) | ((unsigned)f2bf(a.w * QSCALE) << 16);
        pk.u[2] = f2bf(b.x * QSCALE) | ((unsigned)f2bf(b.y * QSCALE) << 16);
        pk.u[3] = f2bf(b.z * QSCALE) | ((unsigned)f2bf(b.w * QSCALE) << 16);
        bq[ks] = pk.s8;
    }

    union { short8 s8; ushort_t u[8]; } one_u;
#pragma unroll
    for (int i = 0; i < 8; ++i) one_u.u[i] = 0x3F80;
    const short8 ones = one_u.s8;

    f32x4 acco[4];
#pragma unroll
    for (int dn = 0; dn < 4; ++dn) {
        f32x4 z = {0.f, 0.f, 0.f, 0.f};
        acco[dn] = z;
    }
    f32x4 accp = {0.f, 0.f, 0.f, 0.f};

    const int id0 = w * 2;
#define STAGEK(buf, kt)                                                        \
    {                                                                          \
        _Pragma("unroll")                                                      \
        for (int j = 0; j < 2; ++j) {                                          \
            const int id = (id0 + j) * 64 + l;                                 \
            const int r = id >> 3, c = id & 7;                                 \
            const int cs = c ^ (r & 7);                                        \
            gload16(Kh + hbase + (size_t)((kt) * 64 + r) * HDD + cs * 8,       \
                    (void*)(Kl[buf] + (id0 + j) * 512));                       \
        }                                                                      \
    }
#define STAGEV(buf, kt)                                                        \
    {                                                                          \
        _Pragma("unroll")                                                      \
        for (int j = 0; j < 2; ++j) {                                          \
            const int id = (id0 + j) * 64 + l;                                 \
            const int r = id >> 3, c = id & 7;                                 \
            const int cs = c ^ (r & 7);                                        \
            gload16(Vt + vbase + (size_t)r * LL + (kt) * 64 + cs * 8,          \
                    (void*)(Vl[buf] + (id0 + j) * 512));                       \
        }                                                                      \
    }

    constexpr int NT = LL / 64;
    const f32x4 z4 = {0.f, 0.f, 0.f, 0.f};

    // prologue: oldest {K0,K1,V0} then newest {K2,V1}; vmcnt(4) -> K0,K1,V0 in
    STAGEK(0, 0);
    STAGEK(1, 1);
    STAGEV(0, 0);
    STAGEK(2, 2);
    STAGEV(1, 1);
    asm volatile("s_waitcnt vmcnt(4)" ::: "memory");
    __builtin_amdgcn_sched_barrier(0);
    __builtin_amdgcn_s_barrier();

    f32x4 accsA[4], accsB[4];
    // pre-loop QK of tile 0 (Kl[0])
    {
        short8 ak[4];
#pragma unroll
        for (int nk = 0; nk < 4; ++nk) {
            const int row = nk * 16 + lr;
            ak[nk] = *(const short8*)(Kl[0] + row * 64 + ((lg) ^ (row & 7)) * 8);
        }
#pragma unroll
        for (int nk = 0; nk < 4; ++nk)
            accsA[nk] = __builtin_amdgcn_mfma_f32_16x16x32_bf16(
                ak[nk], bq[0], z4, 0, 0, 0);
#pragma unroll
        for (int nk = 0; nk < 4; ++nk) {
            const int row = nk * 16 + lr;
            ak[nk] = *(const short8*)(Kl[0] + row * 64 + ((4 | lg) ^ (row & 7)) * 8);
        }
#pragma unroll
        for (int nk = 0; nk < 4; ++nk)
            accsA[nk] = __builtin_amdgcn_mfma_f32_16x16x32_bf16(
                ak[nk], bq[1], accsA[nk], 0, 0, 0);
    }

    int ks3 = 0, kn = 1;   // kt%3 and (kt+1)%3 trackers

#define ATTN_BODY(O_, N_, VB_, KT_)                                            \
    {                                                                          \
        const ushort_t* kb_ = Kl[kn];                                          \
        __builtin_amdgcn_s_setprio(1);                                         \
        {                                                                      \
            short8 ak[4];                                                      \
            _Pragma("unroll")                                                  \
            for (int nk = 0; nk < 4; ++nk) {                                   \
                const int row = nk * 16 + lr;                                  \
                ak[nk] = *(const short8*)(kb_ + row * 64 + ((lg) ^ (row & 7)) * 8); \
            }                                                                  \
            _Pragma("unroll")                                                  \
            for (int nk = 0; nk < 4; ++nk)                                     \
                N_[nk] = __builtin_amdgcn_mfma_f32_16x16x32_bf16(              \
                    ak[nk], bq[0], z4, 0, 0, 0);                               \
            _Pragma("unroll")                                                  \
            for (int nk = 0; nk < 4; ++nk) {                                   \
                const int row = nk * 16 + lr;                                  \
                ak[nk] = *(const short8*)(kb_ + row * 64 + ((4 | lg) ^ (row & 7)) * 8); \
            }                                                                  \
            _Pragma("unroll")                                                  \
            for (int nk = 0; nk < 4; ++nk)                                     \
                N_[nk] = __builtin_amdgcn_mfma_f32_16x16x32_bf16(              \
                    ak[nk], bq[1], N_[nk], 0, 0, 0);                           \
        }                                                                      \
        __builtin_amdgcn_s_setprio(0);                                         \
        float p[4][4];                                                         \
        _Pragma("unroll")                                                      \
        for (int nk = 0; nk < 4; ++nk) {                                       \
            _Pragma("unroll")                                                  \
            for (int r = 0; r < 4; ++r)                                        \
                p[nk][r] = __builtin_amdgcn_exp2f(O_[nk][r]);                  \
        }                                                                      \
        short8 pa[2];                                                          \
        _Pragma("unroll")                                                      \
        for (int ks2 = 0; ks2 < 2; ++ks2) {                                    \
            union { short8 s8; unsigned u[4]; } pk;                            \
            pk.u[0] = pk_hi16(p[2 * ks2][0], p[2 * ks2][1]);                   \
            pk.u[1] = pk_hi16(p[2 * ks2][2], p[2 * ks2][3]);                   \
            pk.u[2] = pk_hi16(p[2 * ks2 + 1][0], p[2 * ks2 + 1][1]);           \
            pk.u[3] = pk_hi16(p[2 * ks2 + 1][2], p[2 * ks2 + 1][3]);           \
            pa[ks2] = pk.s8;                                                   \
        }                                                                      \
        __builtin_amdgcn_s_setprio(1);                                         \
        _Pragma("unroll")                                                      \
        for (int ks2 = 0; ks2 < 2; ++ks2) {                                    \
            short8 bv[4];                                                      \
            _Pragma("unroll")                                                  \
            for (int dn = 0; dn < 4; ++dn) {                                   \
                const int row = dn * 16 + lr;                                  \
                bv[dn] = *(const short8*)(                                     \
                    Vl[VB_] + row * 64 + (((ks2 << 2) | lg) ^ (row & 7)) * 8); \
            }                                                                  \
            accp = __builtin_amdgcn_mfma_f32_16x16x32_bf16(pa[ks2], ones,      \
                                                           accp, 0, 0, 0);    \
            _Pragma("unroll")                                                  \
            for (int dn = 0; dn < 4; ++dn)                                     \
                acco[dn] = __builtin_amdgcn_mfma_f32_16x16x32_bf16(            \
                    pa[ks2], bv[dn], acco[dn], 0, 0, 0);                       \
        }                                                                      \
        __builtin_amdgcn_s_setprio(0);                                         \
        __builtin_amdgcn_s_barrier();                                          \
        STAGEK(ks3, (KT_) + 3);                                                \
        STAGEV(VB_, (KT_) + 2);                                                \
        asm volatile("s_waitcnt vmcnt(4)" ::: "memory");                       \
        __builtin_amdgcn_sched_barrier(0);                                     \
        __builtin_amdgcn_s_barrier();                                          \
        { const int tnk = kn + 1; ks3 = kn; kn = (tnk == 3) ? 0 : tnk; }       \
    }

    for (int kt = 0; kt < NT; kt += 2) {
        ATTN_BODY(accsA, accsB, 0, kt);
        ATTN_BODY(accsB, accsA, 1, kt + 1);
    }

    // ---- write: accp[r] is the full row-sum for q = q0+lg*4+r ----
#pragma unroll
    for (int r = 0; r < 4; ++r) {
        const float invl = 1.f / accp[r];
        const int qq = q0 + lg * 4 + r;
        ushort_t* dst = O + (size_t)(n * LL + qq) * EE + h * HDD + lr;
#pragma unroll
        for (int dn = 0; dn < 4; ++dn)
            dst[dn * 16] = f2bf(acco[dn][r] * invl);
    }
#undef ATTN_BODY
#undef STAGEK
#undef STAGEV
}

// ---------------------------------------------------------------------------
// Transpose+convert: in f32 [K][N] -> out bf16 [N][K]
// ---------------------------------------------------------------------------
__global__ __launch_bounds__(256) void tcvt(
    const float* __restrict__ in, ushort_t* __restrict__ out, int K, int N)
{
    __shared__ float T[32][36];
    const int n0 = blockIdx.x * 32, k0 = blockIdx.y * 32;
    const int r = threadIdx.x >> 3, c4 = (threadIdx.x & 7) * 4;
    const float4 v = *(const float4*)(in + (size_t)(k0 + r) * N + n0 + c4);
    T[r][c4] = v.x; T[r][c4 + 1] = v.y; T[r][c4 + 2] = v.z; T[r][c4 + 3] = v.w;
    __syncthreads();
    const unsigned a = f2bf(T[c4][r])     | ((unsigned)f2bf(T[c4 + 1][r]) << 16);
    const unsigned b = f2bf(T[c4 + 2][r]) | ((unsigned)f2bf(T[c4 + 3][r]) << 16);
    uint2 pk; pk.x = a; pk.y = b;
    *(uint2*)(out + (size_t)(n0 + r) * K + k0 + c4) = pk;
}

// ---------------------------------------------------------------------------
// 8-phase 256x256 bf16 MFMA GEMM (ffn1): C = relu(A @ Bt^T + bias), bf16 out.
// ---------------------------------------------------------------------------
__global__ __launch_bounds__(512, 2) void gemm8p(
    const ushort_t* __restrict__ A, const ushort_t* __restrict__ Bt,
    const float* __restrict__ bias, ushort_t* __restrict__ C,
    int M, int N, int K)
{
    __shared__ __align__(16) ushort_t L[2][4][256 * 32];  // 128 KiB

    const int tid = threadIdx.x;
    const int w = tid >> 6, l = tid & 63;
    const int fr = l & 15, lg = l >> 4;
    const int wr = w >> 2, wc = w & 3;

    const int gx = gridDim.x;
    const int nwg = gx * gridDim.y;
    const int bid = blockIdx.y * gx + blockIdx.x;
    int tile = bid;
    if ((nwg & 7) == 0) tile = (bid & 7) * (nwg >> 3) + (bid >> 3);
    const int bx = tile % gx, by = tile / gx;
    const int brow = by * 256, bcol = bx * 256;

    const int NT = K >> 6;
    const int UMAX = NT << 2;

#define STAGE8(u)                                                              \
    if ((u) < UMAX) {                                                          \
        const int tt = (u) >> 2, slot = (u) & 3;                               \
        const int op = slot & 1, kh = slot >> 1;                               \
        const ushort_t* sp = op ? Bt : A;                                      \
        const int rb = op ? bcol : brow;                                       \
        ushort_t* db = (ushort_t*)L[tt & 1][slot];                             \
        _Pragma("unroll")                                                      \
        for (int j = 0; j < 2; ++j) {                                          \
            const int id = j * 512 + tid;                                      \
            const int row = id >> 2, c = id & 3;                               \
            const int cs = c ^ ((row >> 1) & 3);                               \
            gload16(sp + (size_t)(rb + row) * K + tt * 64 + kh * 32 + cs * 8,  \
                    (void*)(db + id * 8));                                     \
        }                                                                      \
    }

    f32x4 acc[8][4];
#pragma unroll
    for (int i = 0; i < 8; ++i)
#pragma unroll
        for (int g = 0; g < 4; ++g) { f32x4 zz = {0.f,0.f,0.f,0.f}; acc[i][g] = zz; }

#pragma unroll
    for (int u = 0; u < 6; ++u) STAGE8(u);
    asm volatile("s_waitcnt vmcnt(4)" ::: "memory");
    __builtin_amdgcn_sched_barrier(0);
    __builtin_amdgcn_s_barrier();

    const int iters = NT >> 1;
    for (int it = 0; it < iters; ++it) {
#pragma unroll
        for (int p = 0; p < 8; ++p) {
            STAGE8(it * 8 + p + 6);
            const int d  = p >> 2;
            const int mh = p & 1, kh = (p >> 1) & 1;
            short8 af[4], bfr[4];
#pragma unroll
            for (int f = 0; f < 4; ++f) {
                const int row = wr * 128 + (mh * 4 + f) * 16 + fr;
                const int ch = lg ^ ((row >> 1) & 3);
                af[f] = *(const short8*)(&L[d][kh * 2][row * 32 + ch * 8]);
            }
#pragma unroll
            for (int g = 0; g < 4; ++g) {
                const int row = wc * 64 + g * 16 + fr;
                const int ch = lg ^ ((row >> 1) & 3);
                bfr[g] = *(const short8*)(&L[d][kh * 2 + 1][row * 32 + ch * 8]);
            }
            __builtin_amdgcn_s_barrier();
            __builtin_amdgcn_s_setprio(1);
#pragma unroll
            for (int f = 0; f < 4; ++f)
#pragma unroll
                for (int g = 0; g < 4; ++g)
                    acc[mh * 4 + f][g] = __builtin_amdgcn_mfma_f32_16x16x32_bf16(
                        af[f], bfr[g], acc[mh * 4 + f][g], 0, 0, 0);
            __builtin_amdgcn_s_setprio(0);
            if (p == 3 || p == 7) {
                asm volatile("s_waitcnt vmcnt(4)" ::: "memory");
                __builtin_amdgcn_sched_barrier(0);
            }
            __builtin_amdgcn_s_barrier();
        }
    }

#pragma unroll
    for (int mi = 0; mi < 8; ++mi) {
#pragma unroll
        for (int g = 0; g < 4; ++g) {
            const int col = bcol + wc * 64 + g * 16 + fr;
            const float bv = bias[col];
#pragma unroll
            for (int r = 0; r < 4; ++r) {
                const int row = brow + wr * 128 + mi * 16 + lg * 4 + r;
                const float v = fmaxf(acc[mi][g][r] + bv, 0.f);
                C[(size_t)row * N + col] = f2bf(v);
            }
        }
    }
#undef STAGE8
}

// ---------------------------------------------------------------------------
// 8-phase 256x128 bf16 MFMA GEMM, split-K partials (proj & ffn2).
// ---------------------------------------------------------------------------
#define SOFF(slot) ((slot) == 0 ? 0 : (slot) == 1 ? 8192 : (slot) == 2 ? 12288 : 20480)

template <int KSPLIT>
__global__ __launch_bounds__(512, 2) void gemm8p_n128(
    const ushort_t* __restrict__ A, const ushort_t* __restrict__ Bt,
    ushort_t* __restrict__ C, int M, int N, int K)
{
    __shared__ __align__(16) ushort_t L[2][24576];  // 96 KiB

    const int tid = threadIdx.x;
    const int w = tid >> 6, l = tid & 63;
    const int fr = l & 15, lg = l >> 4;
    const int wr = w >> 2, wc = w & 3;

    const int z = blockIdx.z;
    const int Keff = K / KSPLIT;
    const int kb = z * Keff;

    const int gx = gridDim.x;
    const int nwg = gx * gridDim.y;
    const int bid = blockIdx.y * gx + blockIdx.x;
    int tile = bid;
    if ((nwg & 7) == 0) tile = (bid & 7) * (nwg >> 3) + (bid >> 3);
    const int bx = tile % gx, by = tile / gx;
    const int brow = by * 256, bcol = bx * 128;

    const int NT = Keff >> 6;
    const int UMAX = NT << 2;

#define STG(u)                                                                 \
    if ((u) < UMAX) {                                                          \
        const int tt = (u) >> 2, slot = (u) & 3;                               \
        const int op = slot & 1, kh = slot >> 1;                               \
        const ushort_t* sp = op ? Bt : A;                                      \
        const int rb = op ? bcol : brow;                                       \
        ushort_t* db = (ushort_t*)L[tt & 1] + SOFF(slot);                      \
        const int nld = op ? 1 : 2;                                            \
        _Pragma("unroll")                                                      \
        for (int j = 0; j < nld; ++j) {                                        \
            const int id = j * 512 + tid;                                      \
            const int row = id >> 2, c = id & 3;                               \
            const int cs = c ^ ((row >> 1) & 3);                               \
            gload16(sp + (size_t)(rb + row) * K + kb + tt * 64 + kh * 32 + cs * 8, \
                    (void*)(db + id * 8));                                     \
        }                                                                      \
    }

    f32x4 acc[8][2];
#pragma unroll
    for (int i = 0; i < 8; ++i)
#pragma unroll
        for (int g = 0; g < 2; ++g) { f32x4 zz = {0.f,0.f,0.f,0.f}; acc[i][g] = zz; }

#pragma unroll
    for (int u = 0; u < 6; ++u) STG(u);
    asm volatile("s_waitcnt vmcnt(3)" ::: "memory");
    __builtin_amdgcn_sched_barrier(0);
    __builtin_amdgcn_s_barrier();

    const int iters = NT >> 1;
    for (int it = 0; it < iters; ++it) {
#pragma unroll
        for (int p = 0; p < 8; ++p) {
            STG(it * 8 + p + 6);
            const int d  = p >> 2;
            const int mh = p & 1, kh = (p >> 1) & 1;
            short8 af[4], bfr[2];
#pragma unroll
            for (int f = 0; f < 4; ++f) {
                const int row = wr * 128 + (mh * 4 + f) * 16 + fr;
                const int ch = lg ^ ((row >> 1) & 3);
                af[f] = *(const short8*)(&L[d][SOFF(kh * 2) + row * 32 + ch * 8]);
            }
#pragma unroll
            for (int g = 0; g < 2; ++g) {
                const int row = wc * 32 + g * 16 + fr;
                const int ch = lg ^ ((row >> 1) & 3);
                bfr[g] = *(const short8*)(&L[d][SOFF(kh * 2 + 1) + row * 32 + ch * 8]);
            }
            __builtin_amdgcn_s_barrier();
            __builtin_amdgcn_s_setprio(1);
#pragma unroll
            for (int f = 0; f < 4; ++f)
#pragma unroll
                for (int g = 0; g < 2; ++g)
                    acc[mh * 4 + f][g] = __builtin_amdgcn_mfma_f32_16x16x32_bf16(
                        af[f], bfr[g], acc[mh * 4 + f][g], 0, 0, 0);
            __builtin_amdgcn_s_setprio(0);
            if (p == 3 || p == 7) {
                asm volatile("s_waitcnt vmcnt(3)" ::: "memory");
                __builtin_amdgcn_sched_barrier(0);
            }
            __builtin_amdgcn_s_barrier();
        }
    }

    ushort_t* Cb = C + (size_t)z * M * N;
#pragma unroll
    for (int mi = 0; mi < 8; ++mi) {
#pragma unroll
        for (int g = 0; g < 2; ++g) {
            const int col = bcol + wc * 32 + g * 16 + fr;
#pragma unroll
            for (int r = 0; r < 4; ++r) {
                const int row = brow + wr * 128 + mi * 16 + lg * 4 + r;
                Cb[(size_t)row * N + col] = f2bf(acc[mi][g][r]);
            }
        }
    }
#undef STG
}

// ---------------------------------------------------------------------------
// LN1: x = LN(p0 + p1 + b_out + query), p bf16 / query f32; bf16 out.
// ---------------------------------------------------------------------------
__global__ __launch_bounds__(256) void ln_mid(
    const ushort_t* __restrict__ y0, const ushort_t* __restrict__ y1,
    const float* __restrict__ qres, const float* __restrict__ b0,
    const float* __restrict__ g, const float* __restrict__ b,
    ushort_t* __restrict__ out)
{
    const int row = blockIdx.x;
    const int t = threadIdx.x;
    const size_t off = (size_t)row * EE;
    const uint2 a = ((const uint2*)(y0 + off))[t];
    const uint2 c = ((const uint2*)(y1 + off))[t];
    const float4 qq = ((const float4*)(qres + off))[t];
    const float4 b04 = ((const float4*)b0)[t];
    float x[4];
    x[0] = bf2f(a.x & 0xffff) + bf2f(c.x & 0xffff) + qq.x + b04.x;
    x[1] = bf2f(a.x >> 16)    + bf2f(c.x >> 16)    + qq.y + b04.y;
    x[2] = bf2f(a.y & 0xffff) + bf2f(c.y & 0xffff) + qq.z + b04.z;
    x[3] = bf2f(a.y >> 16)    + bf2f(c.y >> 16)    + qq.w + b04.w;

    float s = 0.f, ss = 0.f;
#pragma unroll
    for (int i = 0; i < 4; ++i) { s += x[i]; ss += x[i] * x[i]; }
#pragma unroll
    for (int o = 1; o < 64; o <<= 1) {
        s  += __shfl_xor(s, o, 64);
        ss += __shfl_xor(ss, o, 64);
    }
    __shared__ float sm[8];
    const int wid = t >> 6;
    if ((t & 63) == 0) { sm[wid * 2] = s; sm[wid * 2 + 1] = ss; }
    __syncthreads();
    const float stot  = sm[0] + sm[2] + sm[4] + sm[6];
    const float sstot = sm[1] + sm[3] + sm[5] + sm[7];
    const float mu  = stot * (1.f / EE);
    const float inv = rsqrtf(sstot * (1.f / EE) - mu * mu + LN_EPS);

    const float4 gg = ((const float4*)g)[t];
    const float4 bb = ((const float4*)b)[t];
    uint2 pk;
    pk.x = f2bf((x[0] - mu) * inv * gg.x + bb.x) |
           ((unsigned)f2bf((x[1] - mu) * inv * gg.y + bb.y) << 16);
    pk.y = f2bf((x[2] - mu) * inv * gg.z + bb.z) |
           ((unsigned)f2bf((x[3] - mu) * inv * gg.w + bb.w) << 16);
    ((uint2*)(out + off))[t] = pk;
}

// ---------------------------------------------------------------------------
// LN2: out = LN(y0 + y1 + b2 + x), all-bf16 inputs, f32 out.
// ---------------------------------------------------------------------------
__global__ __launch_bounds__(256) void ln_out(
    const ushort_t* __restrict__ y0, const ushort_t* __restrict__ y1,
    const ushort_t* __restrict__ xb, const float* __restrict__ b2,
    const float* __restrict__ g, const float* __restrict__ be,
    float* __restrict__ out)
{
    const int row = blockIdx.x;
    const int t = threadIdx.x;
    const size_t off = (size_t)row * EE;
    const uint2 a = ((const uint2*)(y0 + off))[t];
    const uint2 b = ((const uint2*)(y1 + off))[t];
    const uint2 c = ((const uint2*)(xb + off))[t];
    const float4 bb2 = ((const float4*)b2)[t];
    float x[4];
    x[0] = bf2f(a.x & 0xffff) + bf2f(b.x & 0xffff) + bf2f(c.x & 0xffff) + bb2.x;
    x[1] = bf2f(a.x >> 16)    + bf2f(b.x >> 16)    + bf2f(c.x >> 16)    + bb2.y;
    x[2] = bf2f(a.y & 0xffff) + bf2f(b.y & 0xffff) + bf2f(c.y & 0xffff) + bb2.z;
    x[3] = bf2f(a.y >> 16)    + bf2f(b.y >> 16)    + bf2f(c.y >> 16)    + bb2.w;

    float s = 0.f, ss = 0.f;
#pragma unroll
    for (int i = 0; i < 4; ++i) { s += x[i]; ss += x[i] * x[i]; }
#pragma unroll
    for (int o = 1; o < 64; o <<= 1) {
        s  += __shfl_xor(s, o, 64);
        ss += __shfl_xor(ss, o, 64);
    }
    __shared__ float sm[8];
    const int wid = t >> 6;
    if ((t & 63) == 0) { sm[wid * 2] = s; sm[wid * 2 + 1] = ss; }
    __syncthreads();
    const float stot  = sm[0] + sm[2] + sm[4] + sm[6];
    const float sstot = sm[1] + sm[3] + sm[5] + sm[7];
    const float mu  = stot * (1.f / EE);
    const float inv = rsqrtf(sstot * (1.f / EE) - mu * mu + LN_EPS);

    const float4 gg = ((const float4*)g)[t];
    const float4 bb = ((const float4*)be)[t];
    float4 o;
    o.x = (x[0] - mu) * inv * gg.x + bb.x;
    o.y = (x[1] - mu) * inv * gg.y + bb.y;
    o.z = (x[2] - mu) * inv * gg.z + bb.z;
    o.w = (x[3] - mu) * inv * gg.w + bb.w;
    ((float4*)(out + off))[t] = o;
}

// ---------------------------------------------------------------------------
extern "C" void kernel_launch(void* const* d_in, const int* in_sizes, int n_in,
                              void* d_out, int out_size, void* d_ws, size_t ws_size,
                              hipStream_t stream) {
    (void)in_sizes; (void)n_in; (void)out_size; (void)ws_size;
    const float* value = (const float*)d_in[0];
    const float* key   = (const float*)d_in[1];
    const float* query = (const float*)d_in[2];
    const float* w_out = (const float*)d_in[3];
    const float* b_out = (const float*)d_in[4];
    const float* w1    = (const float*)d_in[5];
    const float* b1    = (const float*)d_in[6];
    const float* w2    = (const float*)d_in[7];
    const float* b2    = (const float*)d_in[8];
    const float* g1    = (const float*)d_in[9];
    const float* be1   = (const float*)d_in[10];
    const float* g2    = (const float*)d_in[11];
    const float* be2   = (const float*)d_in[12];
    float* out = (float*)d_out;

    const int M = NB * LL;  // 4096
    char* base = (char*)d_ws;
    ushort_t* attn_bf = (ushort_t*)(base);                      //  8 MB
    ushort_t* x_bf    = (ushort_t*)(base + (8ull  << 20));      //  8 MB
    char*     hregion = base + (16ull << 20);                   // 32 MB
    ushort_t* h_bf    = (ushort_t*)hregion;                     //  (post-attn)
    ushort_t* Kh      = (ushort_t*)(hregion);                   //  8 MB (pre-attn)
    ushort_t* Vt      = (ushort_t*)(hregion + (8ull  << 20));   //  8 MB
    ushort_t* y01     = (ushort_t*)(base + (48ull << 20));      // 16 MB (2 partials)
    ushort_t* w0T     = (ushort_t*)(base + (64ull << 20));      //  2 MB
    ushort_t* w1T     = (ushort_t*)(base + (66ull << 20));      //  8 MB
    ushort_t* w2T     = (ushort_t*)(base + (74ull << 20));      //  8 MB (ends 82)

    tcvt<<<dim3(EE / 32, EE / 32), 256, 0, stream>>>(w_out, w0T, EE, EE);
    tcvt<<<dim3(FFD / 32, EE / 32), 256, 0, stream>>>(w1, w1T, EE, FFD);
    tcvt<<<dim3(EE / 32, FFD / 32), 256, 0, stream>>>(w2, w2T, FFD, EE);

    k_cvt<<<NB * HH * LL / 32, 256, 0, stream>>>(key, Kh);
    v_cvt_t<<<dim3(LL / 64, HH, NB), 256, 0, stream>>>(value, Vt);

    attn_mfma<<<dim3(NB * HH * LL / 64), 256, 0, stream>>>(query, Kh, Vt,
                                                           attn_bf);

    // proj: split-K=2 partials (8-phase 256x128), bias+residual fused in LN1
    gemm8p_n128<2><<<dim3(EE / 128, M / 256, 2), 512, 0, stream>>>(
        attn_bf, w0T, y01, M, EE, EE);
    ln_mid<<<M, 256, 0, stream>>>(y01, y01 + (size_t)M * EE, query, b_out,
                                  g1, be1, x_bf);

    // ffn1: [4096,4096] = relu(x_bf @ w1T + b1), bf16 out (8-phase 256x256)
    gemm8p<<<dim3(FFD / 256, M / 256), 512, 0, stream>>>(x_bf, w1T, b1, h_bf,
                                                         M, FFD, EE);
    // ffn2: split-K=2 partials (8-phase 256x128)
    gemm8p_n128<2><<<dim3(EE / 128, M / 256, 2), 512, 0, stream>>>(
        h_bf, w2T, y01, M, EE, FFD);
    ln_out<<<M, 256, 0, stream>>>(y01, y01 + (size_t)M * EE, x_bf, b2, g2, be2,
                                  out);
}

// Round 14
// 178.180 us; speedup vs baseline: 1.0498x; 1.0498x over previous
//
#include <hip/hip_runtime.h>
#include <hip/hip_bf16.h>

#define NB 2
#define LL 2048
#define EE 1024
#define HH 16
#define HDD 64
#define FFD 4096

typedef unsigned short ushort_t;
typedef __attribute__((ext_vector_type(8))) short short8;
typedef __attribute__((ext_vector_type(4))) float f32x4;

constexpr float LN_EPS = 1e-5f;
constexpr float QSCALE = 0.03125f * 1.44269504088896340736f;  // 1/32 * log2(e)

__device__ inline ushort_t f2bf(float f) {
    union { __hip_bfloat16 b; ushort_t u; } v;
    v.b = __float2bfloat16(f);
    return v.u;
}
__device__ inline float bf2f(unsigned us) {
    union { unsigned u; float f; } v; v.u = us << 16; return v.f;
}
// pack trunc-bf16(lo) | trunc-bf16(hi)<<16 in ONE v_perm_b32
__device__ inline unsigned pk_hi16(float lo, float hi) {
    const unsigned sel = 0x07060302u;
    unsigned r;
    asm("v_perm_b32 %0, %1, %2, %3" : "=v"(r) : "v"(hi), "v"(lo), "s"(sel));
    return r;
}

__device__ inline void gload16(const void* g, void* lds) {
    __builtin_amdgcn_global_load_lds(
        (const __attribute__((address_space(1))) void*)g,
        (__attribute__((address_space(3))) void*)lds, 16, 0, 0);
}

// ---------------------------------------------------------------------------
// Fused prep: 3x weight transpose-convert + K convert + V convert/transpose.
// Flat grid, block-uniform job decode (syncthreads-safe).
//   [0,1024)      tcvt w_out (K=E,N=E)
//   [1024,5120)   tcvt w1    (K=E,N=FF)
//   [5120,9216)   tcvt w2    (K=FF,N=E)
//   [9216,11264)  k_cvt
//   [11264,12288) v_cvt_t (kv-permuted columns)
// ---------------------------------------------------------------------------
__global__ __launch_bounds__(256) void prep(
    const float* __restrict__ w_out, const float* __restrict__ w1,
    const float* __restrict__ w2, const float* __restrict__ key,
    const float* __restrict__ value,
    ushort_t* __restrict__ w0T, ushort_t* __restrict__ w1T,
    ushort_t* __restrict__ w2T, ushort_t* __restrict__ Kh,
    ushort_t* __restrict__ Vt)
{
    __shared__ float Tsh[64 * 68];
    const int b = blockIdx.x;
    const int t = threadIdx.x;

    if (b < 9216) {
        // ---- transpose+convert f32 [K][N] -> bf16 [N][K] (32x32 tile) ----
        const float* in; ushort_t* outp; int K, N, bx, by;
        if (b < 1024)      { in = w_out; outp = w0T; K = EE;  N = EE;
                             bx = b & 31;             by = b >> 5; }
        else if (b < 5120) { const int i = b - 1024; in = w1; outp = w1T;
                             K = EE;  N = FFD; bx = i & 127; by = i >> 7; }
        else               { const int i = b - 5120; in = w2; outp = w2T;
                             K = FFD; N = EE;  bx = i & 31;  by = i >> 5; }
        const int n0 = bx * 32, k0 = by * 32;
        const int r = t >> 3, c4 = (t & 7) * 4;
        const float4 v = *(const float4*)(in + (size_t)(k0 + r) * N + n0 + c4);
        Tsh[r * 36 + c4]     = v.x; Tsh[r * 36 + c4 + 1] = v.y;
        Tsh[r * 36 + c4 + 2] = v.z; Tsh[r * 36 + c4 + 3] = v.w;
        __syncthreads();
        const unsigned a = f2bf(Tsh[c4 * 36 + r]) |
                           ((unsigned)f2bf(Tsh[(c4 + 1) * 36 + r]) << 16);
        const unsigned bb = f2bf(Tsh[(c4 + 2) * 36 + r]) |
                            ((unsigned)f2bf(Tsh[(c4 + 3) * 36 + r]) << 16);
        uint2 pk; pk.x = a; pk.y = bb;
        *(uint2*)(outp + (size_t)(n0 + r) * K + k0 + c4) = pk;
    } else if (b < 11264) {
        // ---- K convert: [N,L,H,D] f32 -> [N,H,L,D] bf16 ----
        const int g = (b - 9216) * 32 + (t >> 3);
        const int n = g >> 15, h = (g >> 11) & 15, l2 = g & 2047;
        const int d0 = (t & 7) * 8;
        const float* src = key + ((size_t)(n * LL + l2) * HH + h) * HDD + d0;
        const float4 a = *(const float4*)src;
        const float4 bb = *(const float4*)(src + 4);
        uint4 pk;
        pk.x = f2bf(a.x)  | ((unsigned)f2bf(a.y)  << 16);
        pk.y = f2bf(a.z)  | ((unsigned)f2bf(a.w)  << 16);
        pk.z = f2bf(bb.x) | ((unsigned)f2bf(bb.y) << 16);
        pk.w = f2bf(bb.z) | ((unsigned)f2bf(bb.w) << 16);
        *(uint4*)(Kh + (size_t)g * HDD + d0) = pk;
    } else {
        // ---- V convert+transpose -> [N,H,D,L] bf16, kv-permuted cols ----
        const int i = b - 11264;
        const int lb = i & 31, h = (i >> 5) & 15, n = i >> 9;
        const int l0 = lb * 64;
        {
            const int r = t >> 2, c0 = (t & 3) * 16;
            const float* src = value +
                ((size_t)(n * LL + l0 + r) * HH + h) * HDD + c0;
#pragma unroll
            for (int ii = 0; ii < 4; ++ii)
                *(float4*)&Tsh[r * 68 + c0 + 4 * ii] =
                    *(const float4*)(src + 4 * ii);
        }
        __syncthreads();
        {
            const int d = t >> 2, tq = t & 3;
            unsigned u[8];
#pragma unroll
            for (int k = 0; k < 8; ++k) {
                const int c0 = tq * 16 + 2 * k, c1 = c0 + 1;
                const int p0 = (((c0 >> 5) * 2 + ((c0 >> 2) & 1)) << 4) +
                               (((c0 >> 3) & 3) << 2) + (c0 & 3);
                const int p1 = (((c1 >> 5) * 2 + ((c1 >> 2) & 1)) << 4) +
                               (((c1 >> 3) & 3) << 2) + (c1 & 3);
                u[k] = f2bf(Tsh[p0 * 68 + d]) |
                       ((unsigned)f2bf(Tsh[p1 * 68 + d]) << 16);
            }
            ushort_t* dst = Vt + ((size_t)(n * HH + h) * HDD + d) * LL
                               + l0 + tq * 16;
            uint4 q0; q0.x = u[0]; q0.y = u[1]; q0.z = u[2]; q0.w = u[3];
            uint4 q1; q1.x = u[4]; q1.y = u[5]; q1.z = u[6]; q1.w = u[7];
            *(uint4*)(dst)     = q0;
            *(uint4*)(dst + 8) = q1;
        }
    }
}

// ---------------------------------------------------------------------------
// MFMA flash attention, software-pipelined (QK one tile ahead), stage-K at
// top of iter (pointer strength-reduced), K 3-deep / V 2-deep LDS (40KB),
// counted vmcnt(4). Swapped QK^T, in-register P (v_perm pack), native v_exp,
// ones-column row-sum, XCD-bijective mapping. Block = (n,h,64 q), 4 waves.
// ---------------------------------------------------------------------------
__global__ __launch_bounds__(256) void attn_mfma(
    const float* __restrict__ Qf,     // [N,L,H,D] f32 (raw query)
    const ushort_t* __restrict__ Kh,  // [N,H,L,D] bf16
    const ushort_t* __restrict__ Vt,  // [N,H,D,L] bf16 kv-permuted
    ushort_t* __restrict__ O)         // [N,L,E] bf16
{
    const int s = blockIdx.x;          // grid = 1024
    const int xcd = s & 7, seq = s >> 3;
    const int qb = seq & 31, tt = seq >> 5;
    const int h = ((tt & 1) << 3) | xcd;
    const int n = tt >> 1;

    const int t = threadIdx.x, w = t >> 6, l = t & 63;
    const int lr = l & 15, lg = l >> 4;

    __shared__ __align__(16) ushort_t Kl[3][64 * 64];  // 24 KB
    __shared__ __align__(16) ushort_t Vl[2][64 * 64];  // 16 KB

    const size_t hbase = ((size_t)n * HH + h) * LL * HDD;
    const size_t vbase = ((size_t)n * HH + h) * HDD * LL;
    const int q0 = qb * 64 + w * 16;

    // Q fragments (B-operand), converted+scaled in-kernel
    short8 bq[2];
#pragma unroll
    for (int ks = 0; ks < 2; ++ks) {
        const float* qsrc = Qf + ((size_t)(n * LL + q0 + lr) * HH + h) * HDD
                               + ks * 32 + lg * 8;
        const float4 a = *(const float4*)qsrc;
        const float4 b = *(const float4*)(qsrc + 4);
        union { short8 s8; unsigned u[4]; } pk;
        pk.u[0] = f2bf(a.x * QSCALE) | ((unsigned)f2bf(a.y * QSCALE) << 16);
        pk.u[1] = f2bf(a.z * QSCALE) | ((unsigned)f2bf(a.w * QSCALE) << 16);
        pk.u[2] = f2bf(b.x * QSCALE) | ((unsigned)f2bf(b.y * QSCALE) << 16);
        pk.u[3] = f2bf(b.z * QSCALE) | ((unsigned)f2bf(b.w * QSCALE) << 16);
        bq[ks] = pk.s8;
    }

    union { short8 s8; ushort_t u[8]; } one_u;
#pragma unroll
    for (int i = 0; i < 8; ++i) one_u.u[i] = 0x3F80;
    const short8 ones = one_u.s8;

    f32x4 acco[4];
#pragma unroll
    for (int dn = 0; dn < 4; ++dn) {
        f32x4 z = {0.f, 0.f, 0.f, 0.f};
        acco[dn] = z;
    }
    f32x4 accp = {0.f, 0.f, 0.f, 0.f};

    // per-wave staging lanes: j in {0,1}
    const int id0 = w * 2;
    const int idA = id0 * 64 + l,          idB = (id0 + 1) * 64 + l;
    const int rA = idA >> 3,               rB = idB >> 3;
    const int csA = (idA & 7) ^ (rA & 7),  csB = (idB & 7) ^ (rB & 7);
    const ushort_t* kg = Kh + hbase;
    const ushort_t* vg = Vt + vbase;

    constexpr int NT = LL / 64;
    const f32x4 z4 = {0.f, 0.f, 0.f, 0.f};

    // prologue stage order: K0,K1,V0 (oldest) then K2,V1 -> vmcnt(4)
    gload16(kg + (size_t)(rA) * HDD + csA * 8,        (void*)(Kl[0] + id0 * 512));
    gload16(kg + (size_t)(rB) * HDD + csB * 8,        (void*)(Kl[0] + id0 * 512 + 512));
    gload16(kg + (size_t)(64 + rA) * HDD + csA * 8,   (void*)(Kl[1] + id0 * 512));
    gload16(kg + (size_t)(64 + rB) * HDD + csB * 8,   (void*)(Kl[1] + id0 * 512 + 512));
    gload16(vg + (size_t)rA * LL + csA * 8,           (void*)(Vl[0] + id0 * 512));
    gload16(vg + (size_t)rB * LL + csB * 8,           (void*)(Vl[0] + id0 * 512 + 512));
    gload16(kg + (size_t)(128 + rA) * HDD + csA * 8,  (void*)(Kl[2] + id0 * 512));
    gload16(kg + (size_t)(128 + rB) * HDD + csB * 8,  (void*)(Kl[2] + id0 * 512 + 512));
    gload16(vg + (size_t)rA * LL + 64 + csA * 8,      (void*)(Vl[1] + id0 * 512));
    gload16(vg + (size_t)rB * LL + 64 + csB * 8,      (void*)(Vl[1] + id0 * 512 + 512));
    asm volatile("s_waitcnt vmcnt(4)" ::: "memory");
    __builtin_amdgcn_sched_barrier(0);
    __builtin_amdgcn_s_barrier();

    // running stage pointers: K at tile 3, V at tile 2
    const ushort_t* kp0 = kg + (size_t)(192 + rA) * HDD + csA * 8;
    const ushort_t* kp1 = kg + (size_t)(192 + rB) * HDD + csB * 8;
    const ushort_t* vp0 = vg + (size_t)rA * LL + 128 + csA * 8;
    const ushort_t* vp1 = vg + (size_t)rB * LL + 128 + csB * 8;

    f32x4 accsA[4], accsB[4];
    // pre-loop QK of tile 0 (Kl[0])
    {
        short8 ak[4];
#pragma unroll
        for (int nk = 0; nk < 4; ++nk) {
            const int row = nk * 16 + lr;
            ak[nk] = *(const short8*)(Kl[0] + row * 64 + ((lg) ^ (row & 7)) * 8);
        }
#pragma unroll
        for (int nk = 0; nk < 4; ++nk)
            accsA[nk] = __builtin_amdgcn_mfma_f32_16x16x32_bf16(
                ak[nk], bq[0], z4, 0, 0, 0);
#pragma unroll
        for (int nk = 0; nk < 4; ++nk) {
            const int row = nk * 16 + lr;
            ak[nk] = *(const short8*)(Kl[0] + row * 64 + ((4 | lg) ^ (row & 7)) * 8);
        }
#pragma unroll
        for (int nk = 0; nk < 4; ++nk)
            accsA[nk] = __builtin_amdgcn_mfma_f32_16x16x32_bf16(
                ak[nk], bq[1], accsA[nk], 0, 0, 0);
    }
    __builtin_amdgcn_s_barrier();   // Kl[0] reads done before iter0 overwrites

    int ks3 = 0, kn = 1;   // stage-dest (kt%3) and QK-src ((kt+1)%3) trackers

#define ATTN_BODY(O_, N_, VB_)                                                 \
    {                                                                          \
        /* top: stage K(kt+3) into Kl[ks3] (WAR-safe, read 1 iter ago) */      \
        gload16(kp0, (void*)(Kl[ks3] + id0 * 512));                            \
        gload16(kp1, (void*)(Kl[ks3] + id0 * 512 + 512));                      \
        kp0 += 4096; kp1 += 4096;                                              \
        const ushort_t* kb_ = Kl[kn];                                          \
        __builtin_amdgcn_s_setprio(1);                                         \
        {                                                                      \
            short8 ak[4];                                                      \
            _Pragma("unroll")                                                  \
            for (int nk = 0; nk < 4; ++nk) {                                   \
                const int row = nk * 16 + lr;                                  \
                ak[nk] = *(const short8*)(kb_ + row * 64 + ((lg) ^ (row & 7)) * 8); \
            }                                                                  \
            _Pragma("unroll")                                                  \
            for (int nk = 0; nk < 4; ++nk)                                     \
                N_[nk] = __builtin_amdgcn_mfma_f32_16x16x32_bf16(              \
                    ak[nk], bq[0], z4, 0, 0, 0);                               \
            _Pragma("unroll")                                                  \
            for (int nk = 0; nk < 4; ++nk) {                                   \
                const int row = nk * 16 + lr;                                  \
                ak[nk] = *(const short8*)(kb_ + row * 64 + ((4 | lg) ^ (row & 7)) * 8); \
            }                                                                  \
            _Pragma("unroll")                                                  \
            for (int nk = 0; nk < 4; ++nk)                                     \
                N_[nk] = __builtin_amdgcn_mfma_f32_16x16x32_bf16(              \
                    ak[nk], bq[1], N_[nk], 0, 0, 0);                           \
        }                                                                      \
        __builtin_amdgcn_s_setprio(0);                                         \
        float p[4][4];                                                         \
        _Pragma("unroll")                                                      \
        for (int nk = 0; nk < 4; ++nk) {                                       \
            _Pragma("unroll")                                                  \
            for (int r = 0; r < 4; ++r)                                        \
                p[nk][r] = __builtin_amdgcn_exp2f(O_[nk][r]);                  \
        }                                                                      \
        short8 pa[2];                                                          \
        _Pragma("unroll")                                                      \
        for (int ks2 = 0; ks2 < 2; ++ks2) {                                    \
            union { short8 s8; unsigned u[4]; } pk;                            \
            pk.u[0] = pk_hi16(p[2 * ks2][0], p[2 * ks2][1]);                   \
            pk.u[1] = pk_hi16(p[2 * ks2][2], p[2 * ks2][3]);                   \
            pk.u[2] = pk_hi16(p[2 * ks2 + 1][0], p[2 * ks2 + 1][1]);           \
            pk.u[3] = pk_hi16(p[2 * ks2 + 1][2], p[2 * ks2 + 1][3]);           \
            pa[ks2] = pk.s8;                                                   \
        }                                                                      \
        __builtin_amdgcn_s_setprio(1);                                         \
        _Pragma("unroll")                                                      \
        for (int ks2 = 0; ks2 < 2; ++ks2) {                                    \
            short8 bv[4];                                                      \
            _Pragma("unroll")                                                  \
            for (int dn = 0; dn < 4; ++dn) {                                   \
                const int row = dn * 16 + lr;                                  \
                bv[dn] = *(const short8*)(                                     \
                    Vl[VB_] + row * 64 + (((ks2 << 2) | lg) ^ (row & 7)) * 8); \
            }                                                                  \
            accp = __builtin_amdgcn_mfma_f32_16x16x32_bf16(pa[ks2], ones,      \
                                                           accp, 0, 0, 0);    \
            _Pragma("unroll")                                                  \
            for (int dn = 0; dn < 4; ++dn)                                     \
                acco[dn] = __builtin_amdgcn_mfma_f32_16x16x32_bf16(            \
                    pa[ks2], bv[dn], acco[dn], 0, 0, 0);                       \
        }                                                                      \
        __builtin_amdgcn_s_setprio(0);                                         \
        __builtin_amdgcn_s_barrier();                                          \
        gload16(vp0, (void*)(Vl[VB_] + id0 * 512));                            \
        gload16(vp1, (void*)(Vl[VB_] + id0 * 512 + 512));                      \
        vp0 += 64; vp1 += 64;                                                  \
        asm volatile("s_waitcnt vmcnt(4)" ::: "memory");                       \
        __builtin_amdgcn_sched_barrier(0);                                     \
        __builtin_amdgcn_s_barrier();                                          \
        { const int tnk = kn + 1; ks3 = kn; kn = (tnk == 3) ? 0 : tnk; }       \
    }

    for (int kt = 0; kt < NT; kt += 2) {
        ATTN_BODY(accsA, accsB, 0);
        ATTN_BODY(accsB, accsA, 1);
    }

    // ---- write: accp[r] is the full row-sum for q = q0+lg*4+r ----
#pragma unroll
    for (int r = 0; r < 4; ++r) {
        const float invl = 1.f / accp[r];
        const int qq = q0 + lg * 4 + r;
        ushort_t* dst = O + (size_t)(n * LL + qq) * EE + h * HDD + lr;
#pragma unroll
        for (int dn = 0; dn < 4; ++dn)
            dst[dn * 16] = f2bf(acco[dn][r] * invl);
    }
#undef ATTN_BODY
}

// ---------------------------------------------------------------------------
// 8-phase 256x256 bf16 MFMA GEMM (ffn1): C = relu(A @ Bt^T + bias), bf16 out.
// ---------------------------------------------------------------------------
__global__ __launch_bounds__(512, 2) void gemm8p(
    const ushort_t* __restrict__ A, const ushort_t* __restrict__ Bt,
    const float* __restrict__ bias, ushort_t* __restrict__ C,
    int M, int N, int K)
{
    __shared__ __align__(16) ushort_t L[2][4][256 * 32];  // 128 KiB

    const int tid = threadIdx.x;
    const int w = tid >> 6, l = tid & 63;
    const int fr = l & 15, lg = l >> 4;
    const int wr = w >> 2, wc = w & 3;

    const int gx = gridDim.x;
    const int nwg = gx * gridDim.y;
    const int bid = blockIdx.y * gx + blockIdx.x;
    int tile = bid;
    if ((nwg & 7) == 0) tile = (bid & 7) * (nwg >> 3) + (bid >> 3);
    const int bx = tile % gx, by = tile / gx;
    const int brow = by * 256, bcol = bx * 256;

    const int NT = K >> 6;
    const int UMAX = NT << 2;

#define STAGE8(u)                                                              \
    if ((u) < UMAX) {                                                          \
        const int tt = (u) >> 2, slot = (u) & 3;                               \
        const int op = slot & 1, kh = slot >> 1;                               \
        const ushort_t* sp = op ? Bt : A;                                      \
        const int rb = op ? bcol : brow;                                       \
        ushort_t* db = (ushort_t*)L[tt & 1][slot];                             \
        _Pragma("unroll")                                                      \
        for (int j = 0; j < 2; ++j) {                                          \
            const int id = j * 512 + tid;                                      \
            const int row = id >> 2, c = id & 3;                               \
            const int cs = c ^ ((row >> 1) & 3);                               \
            gload16(sp + (size_t)(rb + row) * K + tt * 64 + kh * 32 + cs * 8,  \
                    (void*)(db + id * 8));                                     \
        }                                                                      \
    }

    f32x4 acc[8][4];
#pragma unroll
    for (int i = 0; i < 8; ++i)
#pragma unroll
        for (int g = 0; g < 4; ++g) { f32x4 zz = {0.f,0.f,0.f,0.f}; acc[i][g] = zz; }

#pragma unroll
    for (int u = 0; u < 6; ++u) STAGE8(u);
    asm volatile("s_waitcnt vmcnt(4)" ::: "memory");
    __builtin_amdgcn_sched_barrier(0);
    __builtin_amdgcn_s_barrier();

    const int iters = NT >> 1;
    for (int it = 0; it < iters; ++it) {
#pragma unroll
        for (int p = 0; p < 8; ++p) {
            STAGE8(it * 8 + p + 6);
            const int d  = p >> 2;
            const int mh = p & 1, kh = (p >> 1) & 1;
            short8 af[4], bfr[4];
#pragma unroll
            for (int f = 0; f < 4; ++f) {
                const int row = wr * 128 + (mh * 4 + f) * 16 + fr;
                const int ch = lg ^ ((row >> 1) & 3);
                af[f] = *(const short8*)(&L[d][kh * 2][row * 32 + ch * 8]);
            }
#pragma unroll
            for (int g = 0; g < 4; ++g) {
                const int row = wc * 64 + g * 16 + fr;
                const int ch = lg ^ ((row >> 1) & 3);
                bfr[g] = *(const short8*)(&L[d][kh * 2 + 1][row * 32 + ch * 8]);
            }
            __builtin_amdgcn_s_barrier();
            __builtin_amdgcn_s_setprio(1);
#pragma unroll
            for (int f = 0; f < 4; ++f)
#pragma unroll
                for (int g = 0; g < 4; ++g)
                    acc[mh * 4 + f][g] = __builtin_amdgcn_mfma_f32_16x16x32_bf16(
                        af[f], bfr[g], acc[mh * 4 + f][g], 0, 0, 0);
            __builtin_amdgcn_s_setprio(0);
            if (p == 3 || p == 7) {
                asm volatile("s_waitcnt vmcnt(4)" ::: "memory");
                __builtin_amdgcn_sched_barrier(0);
            }
            __builtin_amdgcn_s_barrier();
        }
    }

#pragma unroll
    for (int mi = 0; mi < 8; ++mi) {
#pragma unroll
        for (int g = 0; g < 4; ++g) {
            const int col = bcol + wc * 64 + g * 16 + fr;
            const float bv = bias[col];
#pragma unroll
            for (int r = 0; r < 4; ++r) {
                const int row = brow + wr * 128 + mi * 16 + lg * 4 + r;
                const float v = fmaxf(acc[mi][g][r] + bv, 0.f);
                C[(size_t)row * N + col] = f2bf(v);
            }
        }
    }
#undef STAGE8
}

// ---------------------------------------------------------------------------
// 8-phase 256x128 bf16 MFMA GEMM, split-K partials (proj & ffn2).
// ---------------------------------------------------------------------------
#define SOFF(slot) ((slot) == 0 ? 0 : (slot) == 1 ? 8192 : (slot) == 2 ? 12288 : 20480)

template <int KSPLIT>
__global__ __launch_bounds__(512, 2) void gemm8p_n128(
    const ushort_t* __restrict__ A, const ushort_t* __restrict__ Bt,
    ushort_t* __restrict__ C, int M, int N, int K)
{
    __shared__ __align__(16) ushort_t L[2][24576];  // 96 KiB

    const int tid = threadIdx.x;
    const int w = tid >> 6, l = tid & 63;
    const int fr = l & 15, lg = l >> 4;
    const int wr = w >> 2, wc = w & 3;

    const int z = blockIdx.z;
    const int Keff = K / KSPLIT;
    const int kb = z * Keff;

    const int gx = gridDim.x;
    const int nwg = gx * gridDim.y;
    const int bid = blockIdx.y * gx + blockIdx.x;
    int tile = bid;
    if ((nwg & 7) == 0) tile = (bid & 7) * (nwg >> 3) + (bid >> 3);
    const int bx = tile % gx, by = tile / gx;
    const int brow = by * 256, bcol = bx * 128;

    const int NT = Keff >> 6;
    const int UMAX = NT << 2;

#define STG(u)                                                                 \
    if ((u) < UMAX) {                                                          \
        const int tt = (u) >> 2, slot = (u) & 3;                               \
        const int op = slot & 1, kh = slot >> 1;                               \
        const ushort_t* sp = op ? Bt : A;                                      \
        const int rb = op ? bcol : brow;                                       \
        ushort_t* db = (ushort_t*)L[tt & 1] + SOFF(slot);                      \
        const int nld = op ? 1 : 2;                                            \
        _Pragma("unroll")                                                      \
        for (int j = 0; j < nld; ++j) {                                        \
            const int id = j * 512 + tid;                                      \
            const int row = id >> 2, c = id & 3;                               \
            const int cs = c ^ ((row >> 1) & 3);                               \
            gload16(sp + (size_t)(rb + row) * K + kb + tt * 64 + kh * 32 + cs * 8, \
                    (void*)(db + id * 8));                                     \
        }                                                                      \
    }

    f32x4 acc[8][2];
#pragma unroll
    for (int i = 0; i < 8; ++i)
#pragma unroll
        for (int g = 0; g < 2; ++g) { f32x4 zz = {0.f,0.f,0.f,0.f}; acc[i][g] = zz; }

#pragma unroll
    for (int u = 0; u < 6; ++u) STG(u);
    asm volatile("s_waitcnt vmcnt(3)" ::: "memory");
    __builtin_amdgcn_sched_barrier(0);
    __builtin_amdgcn_s_barrier();

    const int iters = NT >> 1;
    for (int it = 0; it < iters; ++it) {
#pragma unroll
        for (int p = 0; p < 8; ++p) {
            STG(it * 8 + p + 6);
            const int d  = p >> 2;
            const int mh = p & 1, kh = (p >> 1) & 1;
            short8 af[4], bfr[2];
#pragma unroll
            for (int f = 0; f < 4; ++f) {
                const int row = wr * 128 + (mh * 4 + f) * 16 + fr;
                const int ch = lg ^ ((row >> 1) & 3);
                af[f] = *(const short8*)(&L[d][SOFF(kh * 2) + row * 32 + ch * 8]);
            }
#pragma unroll
            for (int g = 0; g < 2; ++g) {
                const int row = wc * 32 + g * 16 + fr;
                const int ch = lg ^ ((row >> 1) & 3);
                bfr[g] = *(const short8*)(&L[d][SOFF(kh * 2 + 1) + row * 32 + ch * 8]);
            }
            __builtin_amdgcn_s_barrier();
            __builtin_amdgcn_s_setprio(1);
#pragma unroll
            for (int f = 0; f < 4; ++f)
#pragma unroll
                for (int g = 0; g < 2; ++g)
                    acc[mh * 4 + f][g] = __builtin_amdgcn_mfma_f32_16x16x32_bf16(
                        af[f], bfr[g], acc[mh * 4 + f][g], 0, 0, 0);
            __builtin_amdgcn_s_setprio(0);
            if (p == 3 || p == 7) {
                asm volatile("s_waitcnt vmcnt(3)" ::: "memory");
                __builtin_amdgcn_sched_barrier(0);
            }
            __builtin_amdgcn_s_barrier();
        }
    }

    ushort_t* Cb = C + (size_t)z * M * N;
#pragma unroll
    for (int mi = 0; mi < 8; ++mi) {
#pragma unroll
        for (int g = 0; g < 2; ++g) {
            const int col = bcol + wc * 32 + g * 16 + fr;
#pragma unroll
            for (int r = 0; r < 4; ++r) {
                const int row = brow + wr * 128 + mi * 16 + lg * 4 + r;
                Cb[(size_t)row * N + col] = f2bf(acc[mi][g][r]);
            }
        }
    }
#undef STG
}

// ---------------------------------------------------------------------------
// LN1: x = LN(p0 + p1 + b_out + query), p bf16 / query f32; bf16 out.
// ---------------------------------------------------------------------------
__global__ __launch_bounds__(256) void ln_mid(
    const ushort_t* __restrict__ y0, const ushort_t* __restrict__ y1,
    const float* __restrict__ qres, const float* __restrict__ b0,
    const float* __restrict__ g, const float* __restrict__ b,
    ushort_t* __restrict__ out)
{
    const int row = blockIdx.x;
    const int t = threadIdx.x;
    const size_t off = (size_t)row * EE;
    const uint2 a = ((const uint2*)(y0 + off))[t];
    const uint2 c = ((const uint2*)(y1 + off))[t];
    const float4 qq = ((const float4*)(qres + off))[t];
    const float4 b04 = ((const float4*)b0)[t];
    float x[4];
    x[0] = bf2f(a.x & 0xffff) + bf2f(c.x & 0xffff) + qq.x + b04.x;
    x[1] = bf2f(a.x >> 16)    + bf2f(c.x >> 16)    + qq.y + b04.y;
    x[2] = bf2f(a.y & 0xffff) + bf2f(c.y & 0xffff) + qq.z + b04.z;
    x[3] = bf2f(a.y >> 16)    + bf2f(c.y >> 16)    + qq.w + b04.w;

    float s = 0.f, ss = 0.f;
#pragma unroll
    for (int i = 0; i < 4; ++i) { s += x[i]; ss += x[i] * x[i]; }
#pragma unroll
    for (int o = 1; o < 64; o <<= 1) {
        s  += __shfl_xor(s, o, 64);
        ss += __shfl_xor(ss, o, 64);
    }
    __shared__ float sm[8];
    const int wid = t >> 6;
    if ((t & 63) == 0) { sm[wid * 2] = s; sm[wid * 2 + 1] = ss; }
    __syncthreads();
    const float stot  = sm[0] + sm[2] + sm[4] + sm[6];
    const float sstot = sm[1] + sm[3] + sm[5] + sm[7];
    const float mu  = stot * (1.f / EE);
    const float inv = rsqrtf(sstot * (1.f / EE) - mu * mu + LN_EPS);

    const float4 gg = ((const float4*)g)[t];
    const float4 bb = ((const float4*)b)[t];
    uint2 pk;
    pk.x = f2bf((x[0] - mu) * inv * gg.x + bb.x) |
           ((unsigned)f2bf((x[1] - mu) * inv * gg.y + bb.y) << 16);
    pk.y = f2bf((x[2] - mu) * inv * gg.z + bb.z) |
           ((unsigned)f2bf((x[3] - mu) * inv * gg.w + bb.w) << 16);
    ((uint2*)(out + off))[t] = pk;
}

// ---------------------------------------------------------------------------
// LN2: out = LN(y0 + y1 + b2 + x), all-bf16 inputs, f32 out.
// ---------------------------------------------------------------------------
__global__ __launch_bounds__(256) void ln_out(
    const ushort_t* __restrict__ y0, const ushort_t* __restrict__ y1,
    const ushort_t* __restrict__ xb, const float* __restrict__ b2,
    const float* __restrict__ g, const float* __restrict__ be,
    float* __restrict__ out)
{
    const int row = blockIdx.x;
    const int t = threadIdx.x;
    const size_t off = (size_t)row * EE;
    const uint2 a = ((const uint2*)(y0 + off))[t];
    const uint2 b = ((const uint2*)(y1 + off))[t];
    const uint2 c = ((const uint2*)(xb + off))[t];
    const float4 bb2 = ((const float4*)b2)[t];
    float x[4];
    x[0] = bf2f(a.x & 0xffff) + bf2f(b.x & 0xffff) + bf2f(c.x & 0xffff) + bb2.x;
    x[1] = bf2f(a.x >> 16)    + bf2f(b.x >> 16)    + bf2f(c.x >> 16)    + bb2.y;
    x[2] = bf2f(a.y & 0xffff) + bf2f(b.y & 0xffff) + bf2f(c.y & 0xffff) + bb2.z;
    x[3] = bf2f(a.y >> 16)    + bf2f(b.y >> 16)    + bf2f(c.y >> 16)    + bb2.w;

    float s = 0.f, ss = 0.f;
#pragma unroll
    for (int i = 0; i < 4; ++i) { s += x[i]; ss += x[i] * x[i]; }
#pragma unroll
    for (int o = 1; o < 64; o <<= 1) {
        s  += __shfl_xor(s, o, 64);
        ss += __shfl_xor(ss, o, 64);
    }
    __shared__ float sm[8];
    const int wid = t >> 6;
    if ((t & 63) == 0) { sm[wid * 2] = s; sm[wid * 2 + 1] = ss; }
    __syncthreads();
    const float stot  = sm[0] + sm[2] + sm[4] + sm[6];
    const float sstot = sm[1] + sm[3] + sm[5] + sm[7];
    const float mu  = stot * (1.f / EE);
    const float inv = rsqrtf(sstot * (1.f / EE) - mu * mu + LN_EPS);

    const float4 gg = ((const float4*)g)[t];
    const float4 bb = ((const float4*)be)[t];
    float4 o;
    o.x = (x[0] - mu) * inv * gg.x + bb.x;
    o.y = (x[1] - mu) * inv * gg.y + bb.y;
    o.z = (x[2] - mu) * inv * gg.z + bb.z;
    o.w = (x[3] - mu) * inv * gg.w + bb.w;
    ((float4*)(out + off))[t] = o;
}

// ---------------------------------------------------------------------------
extern "C" void kernel_launch(void* const* d_in, const int* in_sizes, int n_in,
                              void* d_out, int out_size, void* d_ws, size_t ws_size,
                              hipStream_t stream) {
    (void)in_sizes; (void)n_in; (void)out_size; (void)ws_size;
    const float* value = (const float*)d_in[0];
    const float* key   = (const float*)d_in[1];
    const float* query = (const float*)d_in[2];
    const float* w_out = (const float*)d_in[3];
    const float* b_out = (const float*)d_in[4];
    const float* w1    = (const float*)d_in[5];
    const float* b1    = (const float*)d_in[6];
    const float* w2    = (const float*)d_in[7];
    const float* b2    = (const float*)d_in[8];
    const float* g1    = (const float*)d_in[9];
    const float* be1   = (const float*)d_in[10];
    const float* g2    = (const float*)d_in[11];
    const float* be2   = (const float*)d_in[12];
    float* out = (float*)d_out;

    const int M = NB * LL;  // 4096
    char* base = (char*)d_ws;
    ushort_t* attn_bf = (ushort_t*)(base);                      //  8 MB
    ushort_t* x_bf    = (ushort_t*)(base + (8ull  << 20));      //  8 MB
    char*     hregion = base + (16ull << 20);                   // 32 MB
    ushort_t* h_bf    = (ushort_t*)hregion;                     //  (post-attn)
    ushort_t* Kh      = (ushort_t*)(hregion);                   //  8 MB (pre-attn)
    ushort_t* Vt      = (ushort_t*)(hregion + (8ull  << 20));   //  8 MB
    ushort_t* y01     = (ushort_t*)(base + (48ull << 20));      // 16 MB (2 partials)
    ushort_t* w0T     = (ushort_t*)(base + (64ull << 20));      //  2 MB
    ushort_t* w1T     = (ushort_t*)(base + (66ull << 20));      //  8 MB
    ushort_t* w2T     = (ushort_t*)(base + (74ull << 20));      //  8 MB (ends 82)

    prep<<<12288, 256, 0, stream>>>(w_out, w1, w2, key, value,
                                    w0T, w1T, w2T, Kh, Vt);

    attn_mfma<<<dim3(NB * HH * LL / 64), 256, 0, stream>>>(query, Kh, Vt,
                                                           attn_bf);

    // proj: split-K=2 partials (8-phase 256x128), bias+residual fused in LN1
    gemm8p_n128<2><<<dim3(EE / 128, M / 256, 2), 512, 0, stream>>>(
        attn_bf, w0T, y01, M, EE, EE);
    ln_mid<<<M, 256, 0, stream>>>(y01, y01 + (size_t)M * EE, query, b_out,
                                  g1, be1, x_bf);

    // ffn1: [4096,4096] = relu(x_bf @ w1T + b1), bf16 out (8-phase 256x256)
    gemm8p<<<dim3(FFD / 256, M / 256), 512, 0, stream>>>(x_bf, w1T, b1, h_bf,
                                                         M, FFD, EE);
    // ffn2: split-K=2 partials (8-phase 256x128)
    gemm8p_n128<2><<<dim3(EE / 128, M / 256, 2), 512, 0, stream>>>(
        h_bf, w2T, y01, M, EE, FFD);
    ln_out<<<M, 256, 0, stream>>>(y01, y01 + (size_t)M * EE, x_bf, b2, g2, be2,
                                  out);
}

// Round 15
// 176.502 us; speedup vs baseline: 1.0598x; 1.0095x over previous
//
#include <hip/hip_runtime.h>
#include <hip/hip_bf16.h>

#define NB 2
#define LL 2048
#define EE 1024
#define HH 16
#define HDD 64
#define FFD 4096

typedef unsigned short ushort_t;
typedef __attribute__((ext_vector_type(8))) short short8;
typedef __attribute__((ext_vector_type(4))) float f32x4;

constexpr float LN_EPS = 1e-5f;
constexpr float QSCALE = 0.03125f * 1.44269504088896340736f;  // 1/32 * log2(e)

__device__ inline ushort_t f2bf(float f) {
    union { __hip_bfloat16 b; ushort_t u; } v;
    v.b = __float2bfloat16(f);
    return v.u;
}
__device__ inline float bf2f(unsigned us) {
    union { unsigned u; float f; } v; v.u = us << 16; return v.f;
}
// pack trunc-bf16(lo) | trunc-bf16(hi)<<16 in ONE v_perm_b32
__device__ inline unsigned pk_hi16(float lo, float hi) {
    const unsigned sel = 0x07060302u;
    unsigned r;
    asm("v_perm_b32 %0, %1, %2, %3" : "=v"(r) : "v"(hi), "v"(lo), "s"(sel));
    return r;
}

__device__ inline void gload16(const void* g, void* lds) {
    __builtin_amdgcn_global_load_lds(
        (const __attribute__((address_space(1))) void*)g,
        (__attribute__((address_space(3))) void*)lds, 16, 0, 0);
}

// ---------------------------------------------------------------------------
// Fused prep: 3x weight transpose-convert + K convert + V convert/transpose.
// ---------------------------------------------------------------------------
__global__ __launch_bounds__(256) void prep(
    const float* __restrict__ w_out, const float* __restrict__ w1,
    const float* __restrict__ w2, const float* __restrict__ key,
    const float* __restrict__ value,
    ushort_t* __restrict__ w0T, ushort_t* __restrict__ w1T,
    ushort_t* __restrict__ w2T, ushort_t* __restrict__ Kh,
    ushort_t* __restrict__ Vt)
{
    __shared__ float Tsh[64 * 68];
    const int b = blockIdx.x;
    const int t = threadIdx.x;

    if (b < 9216) {
        const float* in; ushort_t* outp; int K, N, bx, by;
        if (b < 1024)      { in = w_out; outp = w0T; K = EE;  N = EE;
                             bx = b & 31;             by = b >> 5; }
        else if (b < 5120) { const int i = b - 1024; in = w1; outp = w1T;
                             K = EE;  N = FFD; bx = i & 127; by = i >> 7; }
        else               { const int i = b - 5120; in = w2; outp = w2T;
                             K = FFD; N = EE;  bx = i & 31;  by = i >> 5; }
        const int n0 = bx * 32, k0 = by * 32;
        const int r = t >> 3, c4 = (t & 7) * 4;
        const float4 v = *(const float4*)(in + (size_t)(k0 + r) * N + n0 + c4);
        Tsh[r * 36 + c4]     = v.x; Tsh[r * 36 + c4 + 1] = v.y;
        Tsh[r * 36 + c4 + 2] = v.z; Tsh[r * 36 + c4 + 3] = v.w;
        __syncthreads();
        const unsigned a = f2bf(Tsh[c4 * 36 + r]) |
                           ((unsigned)f2bf(Tsh[(c4 + 1) * 36 + r]) << 16);
        const unsigned bb = f2bf(Tsh[(c4 + 2) * 36 + r]) |
                            ((unsigned)f2bf(Tsh[(c4 + 3) * 36 + r]) << 16);
        uint2 pk; pk.x = a; pk.y = bb;
        *(uint2*)(outp + (size_t)(n0 + r) * K + k0 + c4) = pk;
    } else if (b < 11264) {
        const int g = (b - 9216) * 32 + (t >> 3);
        const int n = g >> 15, h = (g >> 11) & 15, l2 = g & 2047;
        const int d0 = (t & 7) * 8;
        const float* src = key + ((size_t)(n * LL + l2) * HH + h) * HDD + d0;
        const float4 a = *(const float4*)src;
        const float4 bb = *(const float4*)(src + 4);
        uint4 pk;
        pk.x = f2bf(a.x)  | ((unsigned)f2bf(a.y)  << 16);
        pk.y = f2bf(a.z)  | ((unsigned)f2bf(a.w)  << 16);
        pk.z = f2bf(bb.x) | ((unsigned)f2bf(bb.y) << 16);
        pk.w = f2bf(bb.z) | ((unsigned)f2bf(bb.w) << 16);
        *(uint4*)(Kh + (size_t)g * HDD + d0) = pk;
    } else {
        const int i = b - 11264;
        const int lb = i & 31, h = (i >> 5) & 15, n = i >> 9;
        const int l0 = lb * 64;
        {
            const int r = t >> 2, c0 = (t & 3) * 16;
            const float* src = value +
                ((size_t)(n * LL + l0 + r) * HH + h) * HDD + c0;
#pragma unroll
            for (int ii = 0; ii < 4; ++ii)
                *(float4*)&Tsh[r * 68 + c0 + 4 * ii] =
                    *(const float4*)(src + 4 * ii);
        }
        __syncthreads();
        {
            const int d = t >> 2, tq = t & 3;
            unsigned u[8];
#pragma unroll
            for (int k = 0; k < 8; ++k) {
                const int c0 = tq * 16 + 2 * k, c1 = c0 + 1;
                const int p0 = (((c0 >> 5) * 2 + ((c0 >> 2) & 1)) << 4) +
                               (((c0 >> 3) & 3) << 2) + (c0 & 3);
                const int p1 = (((c1 >> 5) * 2 + ((c1 >> 2) & 1)) << 4) +
                               (((c1 >> 3) & 3) << 2) + (c1 & 3);
                u[k] = f2bf(Tsh[p0 * 68 + d]) |
                       ((unsigned)f2bf(Tsh[p1 * 68 + d]) << 16);
            }
            ushort_t* dst = Vt + ((size_t)(n * HH + h) * HDD + d) * LL
                               + l0 + tq * 16;
            uint4 q0; q0.x = u[0]; q0.y = u[1]; q0.z = u[2]; q0.w = u[3];
            uint4 q1; q1.x = u[4]; q1.y = u[5]; q1.z = u[6]; q1.w = u[7];
            *(uint4*)(dst)     = q0;
            *(uint4*)(dst + 8) = q1;
        }
    }
}

// ---------------------------------------------------------------------------
// MFMA flash attention (r14 structure, unchanged).
// ---------------------------------------------------------------------------
__global__ __launch_bounds__(256) void attn_mfma(
    const float* __restrict__ Qf,     // [N,L,H,D] f32 (raw query)
    const ushort_t* __restrict__ Kh,  // [N,H,L,D] bf16
    const ushort_t* __restrict__ Vt,  // [N,H,D,L] bf16 kv-permuted
    ushort_t* __restrict__ O)         // [N,L,E] bf16
{
    const int s = blockIdx.x;          // grid = 1024
    const int xcd = s & 7, seq = s >> 3;
    const int qb = seq & 31, tt = seq >> 5;
    const int h = ((tt & 1) << 3) | xcd;
    const int n = tt >> 1;

    const int t = threadIdx.x, w = t >> 6, l = t & 63;
    const int lr = l & 15, lg = l >> 4;

    __shared__ __align__(16) ushort_t Kl[3][64 * 64];  // 24 KB
    __shared__ __align__(16) ushort_t Vl[2][64 * 64];  // 16 KB

    const size_t hbase = ((size_t)n * HH + h) * LL * HDD;
    const size_t vbase = ((size_t)n * HH + h) * HDD * LL;
    const int q0 = qb * 64 + w * 16;

    short8 bq[2];
#pragma unroll
    for (int ks = 0; ks < 2; ++ks) {
        const float* qsrc = Qf + ((size_t)(n * LL + q0 + lr) * HH + h) * HDD
                               + ks * 32 + lg * 8;
        const float4 a = *(const float4*)qsrc;
        const float4 b = *(const float4*)(qsrc + 4);
        union { short8 s8; unsigned u[4]; } pk;
        pk.u[0] = f2bf(a.x * QSCALE) | ((unsigned)f2bf(a.y * QSCALE) << 16);
        pk.u[1] = f2bf(a.z * QSCALE) | ((unsigned)f2bf(a.w * QSCALE) << 16);
        pk.u[2] = f2bf(b.x * QSCALE) | ((unsigned)f2bf(b.y * QSCALE) << 16);
        pk.u[3] = f2bf(b.z * QSCALE) | ((unsigned)f2bf(b.w * QSCALE) << 16);
        bq[ks] = pk.s8;
    }

    union { short8 s8; ushort_t u[8]; } one_u;
#pragma unroll
    for (int i = 0; i < 8; ++i) one_u.u[i] = 0x3F80;
    const short8 ones = one_u.s8;

    f32x4 acco[4];
#pragma unroll
    for (int dn = 0; dn < 4; ++dn) {
        f32x4 z = {0.f, 0.f, 0.f, 0.f};
        acco[dn] = z;
    }
    f32x4 accp = {0.f, 0.f, 0.f, 0.f};

    const int id0 = w * 2;
    const int idA = id0 * 64 + l,          idB = (id0 + 1) * 64 + l;
    const int rA = idA >> 3,               rB = idB >> 3;
    const int csA = (idA & 7) ^ (rA & 7),  csB = (idB & 7) ^ (rB & 7);
    const ushort_t* kg = Kh + hbase;
    const ushort_t* vg = Vt + vbase;

    constexpr int NT = LL / 64;
    const f32x4 z4 = {0.f, 0.f, 0.f, 0.f};

    gload16(kg + (size_t)(rA) * HDD + csA * 8,        (void*)(Kl[0] + id0 * 512));
    gload16(kg + (size_t)(rB) * HDD + csB * 8,        (void*)(Kl[0] + id0 * 512 + 512));
    gload16(kg + (size_t)(64 + rA) * HDD + csA * 8,   (void*)(Kl[1] + id0 * 512));
    gload16(kg + (size_t)(64 + rB) * HDD + csB * 8,   (void*)(Kl[1] + id0 * 512 + 512));
    gload16(vg + (size_t)rA * LL + csA * 8,           (void*)(Vl[0] + id0 * 512));
    gload16(vg + (size_t)rB * LL + csB * 8,           (void*)(Vl[0] + id0 * 512 + 512));
    gload16(kg + (size_t)(128 + rA) * HDD + csA * 8,  (void*)(Kl[2] + id0 * 512));
    gload16(kg + (size_t)(128 + rB) * HDD + csB * 8,  (void*)(Kl[2] + id0 * 512 + 512));
    gload16(vg + (size_t)rA * LL + 64 + csA * 8,      (void*)(Vl[1] + id0 * 512));
    gload16(vg + (size_t)rB * LL + 64 + csB * 8,      (void*)(Vl[1] + id0 * 512 + 512));
    asm volatile("s_waitcnt vmcnt(4)" ::: "memory");
    __builtin_amdgcn_sched_barrier(0);
    __builtin_amdgcn_s_barrier();

    const ushort_t* kp0 = kg + (size_t)(192 + rA) * HDD + csA * 8;
    const ushort_t* kp1 = kg + (size_t)(192 + rB) * HDD + csB * 8;
    const ushort_t* vp0 = vg + (size_t)rA * LL + 128 + csA * 8;
    const ushort_t* vp1 = vg + (size_t)rB * LL + 128 + csB * 8;

    f32x4 accsA[4], accsB[4];
    {
        short8 ak[4];
#pragma unroll
        for (int nk = 0; nk < 4; ++nk) {
            const int row = nk * 16 + lr;
            ak[nk] = *(const short8*)(Kl[0] + row * 64 + ((lg) ^ (row & 7)) * 8);
        }
#pragma unroll
        for (int nk = 0; nk < 4; ++nk)
            accsA[nk] = __builtin_amdgcn_mfma_f32_16x16x32_bf16(
                ak[nk], bq[0], z4, 0, 0, 0);
#pragma unroll
        for (int nk = 0; nk < 4; ++nk) {
            const int row = nk * 16 + lr;
            ak[nk] = *(const short8*)(Kl[0] + row * 64 + ((4 | lg) ^ (row & 7)) * 8);
        }
#pragma unroll
        for (int nk = 0; nk < 4; ++nk)
            accsA[nk] = __builtin_amdgcn_mfma_f32_16x16x32_bf16(
                ak[nk], bq[1], accsA[nk], 0, 0, 0);
    }
    __builtin_amdgcn_s_barrier();

    int ks3 = 0, kn = 1;

#define ATTN_BODY(O_, N_, VB_)                                                 \
    {                                                                          \
        gload16(kp0, (void*)(Kl[ks3] + id0 * 512));                            \
        gload16(kp1, (void*)(Kl[ks3] + id0 * 512 + 512));                      \
        kp0 += 4096; kp1 += 4096;                                              \
        const ushort_t* kb_ = Kl[kn];                                          \
        __builtin_amdgcn_s_setprio(1);                                         \
        {                                                                      \
            short8 ak[4];                                                      \
            _Pragma("unroll")                                                  \
            for (int nk = 0; nk < 4; ++nk) {                                   \
                const int row = nk * 16 + lr;                                  \
                ak[nk] = *(const short8*)(kb_ + row * 64 + ((lg) ^ (row & 7)) * 8); \
            }                                                                  \
            _Pragma("unroll")                                                  \
            for (int nk = 0; nk < 4; ++nk)                                     \
                N_[nk] = __builtin_amdgcn_mfma_f32_16x16x32_bf16(              \
                    ak[nk], bq[0], z4, 0, 0, 0);                               \
            _Pragma("unroll")                                                  \
            for (int nk = 0; nk < 4; ++nk) {                                   \
                const int row = nk * 16 + lr;                                  \
                ak[nk] = *(const short8*)(kb_ + row * 64 + ((4 | lg) ^ (row & 7)) * 8); \
            }                                                                  \
            _Pragma("unroll")                                                  \
            for (int nk = 0; nk < 4; ++nk)                                     \
                N_[nk] = __builtin_amdgcn_mfma_f32_16x16x32_bf16(              \
                    ak[nk], bq[1], N_[nk], 0, 0, 0);                           \
        }                                                                      \
        __builtin_amdgcn_s_setprio(0);                                         \
        float p[4][4];                                                         \
        _Pragma("unroll")                                                      \
        for (int nk = 0; nk < 4; ++nk) {                                       \
            _Pragma("unroll")                                                  \
            for (int r = 0; r < 4; ++r)                                        \
                p[nk][r] = __builtin_amdgcn_exp2f(O_[nk][r]);                  \
        }                                                                      \
        short8 pa[2];                                                          \
        _Pragma("unroll")                                                      \
        for (int ks2 = 0; ks2 < 2; ++ks2) {                                    \
            union { short8 s8; unsigned u[4]; } pk;                            \
            pk.u[0] = pk_hi16(p[2 * ks2][0], p[2 * ks2][1]);                   \
            pk.u[1] = pk_hi16(p[2 * ks2][2], p[2 * ks2][3]);                   \
            pk.u[2] = pk_hi16(p[2 * ks2 + 1][0], p[2 * ks2 + 1][1]);           \
            pk.u[3] = pk_hi16(p[2 * ks2 + 1][2], p[2 * ks2 + 1][3]);           \
            pa[ks2] = pk.s8;                                                   \
        }                                                                      \
        __builtin_amdgcn_s_setprio(1);                                         \
        _Pragma("unroll")                                                      \
        for (int ks2 = 0; ks2 < 2; ++ks2) {                                    \
            short8 bv[4];                                                      \
            _Pragma("unroll")                                                  \
            for (int dn = 0; dn < 4; ++dn) {                                   \
                const int row = dn * 16 + lr;                                  \
                bv[dn] = *(const short8*)(                                     \
                    Vl[VB_] + row * 64 + (((ks2 << 2) | lg) ^ (row & 7)) * 8); \
            }                                                                  \
            accp = __builtin_amdgcn_mfma_f32_16x16x32_bf16(pa[ks2], ones,      \
                                                           accp, 0, 0, 0);    \
            _Pragma("unroll")                                                  \
            for (int dn = 0; dn < 4; ++dn)                                     \
                acco[dn] = __builtin_amdgcn_mfma_f32_16x16x32_bf16(            \
                    pa[ks2], bv[dn], acco[dn], 0, 0, 0);                       \
        }                                                                      \
        __builtin_amdgcn_s_setprio(0);                                         \
        __builtin_amdgcn_s_barrier();                                          \
        gload16(vp0, (void*)(Vl[VB_] + id0 * 512));                            \
        gload16(vp1, (void*)(Vl[VB_] + id0 * 512 + 512));                      \
        vp0 += 64; vp1 += 64;                                                  \
        asm volatile("s_waitcnt vmcnt(4)" ::: "memory");                       \
        __builtin_amdgcn_sched_barrier(0);                                     \
        __builtin_amdgcn_s_barrier();                                          \
        { const int tnk = kn + 1; ks3 = kn; kn = (tnk == 3) ? 0 : tnk; }       \
    }

    for (int kt = 0; kt < NT; kt += 2) {
        ATTN_BODY(accsA, accsB, 0);
        ATTN_BODY(accsB, accsA, 1);
    }

#pragma unroll
    for (int r = 0; r < 4; ++r) {
        const float invl = 1.f / accp[r];
        const int qq = q0 + lg * 4 + r;
        ushort_t* dst = O + (size_t)(n * LL + qq) * EE + h * HDD + lr;
#pragma unroll
        for (int dn = 0; dn < 4; ++dn)
            dst[dn * 16] = f2bf(acco[dn][r] * invl);
    }
#undef ATTN_BODY
}

// ---------------------------------------------------------------------------
// 8-phase 256x256 bf16 MFMA GEMM (ffn1): C = relu(A @ Bt^T + bias), bf16 out.
// ---------------------------------------------------------------------------
__global__ __launch_bounds__(512, 2) void gemm8p(
    const ushort_t* __restrict__ A, const ushort_t* __restrict__ Bt,
    const float* __restrict__ bias, ushort_t* __restrict__ C,
    int M, int N, int K)
{
    __shared__ __align__(16) ushort_t L[2][4][256 * 32];  // 128 KiB

    const int tid = threadIdx.x;
    const int w = tid >> 6, l = tid & 63;
    const int fr = l & 15, lg = l >> 4;
    const int wr = w >> 2, wc = w & 3;

    const int gx = gridDim.x;
    const int nwg = gx * gridDim.y;
    const int bid = blockIdx.y * gx + blockIdx.x;
    int tile = bid;
    if ((nwg & 7) == 0) tile = (bid & 7) * (nwg >> 3) + (bid >> 3);
    const int bx = tile % gx, by = tile / gx;
    const int brow = by * 256, bcol = bx * 256;

    const int NT = K >> 6;
    const int UMAX = NT << 2;

#define STAGE8(u)                                                              \
    if ((u) < UMAX) {                                                          \
        const int tt = (u) >> 2, slot = (u) & 3;                               \
        const int op = slot & 1, kh = slot >> 1;                               \
        const ushort_t* sp = op ? Bt : A;                                      \
        const int rb = op ? bcol : brow;                                       \
        ushort_t* db = (ushort_t*)L[tt & 1][slot];                             \
        _Pragma("unroll")                                                      \
        for (int j = 0; j < 2; ++j) {                                          \
            const int id = j * 512 + tid;                                      \
            const int row = id >> 2, c = id & 3;                               \
            const int cs = c ^ ((row >> 1) & 3);                               \
            gload16(sp + (size_t)(rb + row) * K + tt * 64 + kh * 32 + cs * 8,  \
                    (void*)(db + id * 8));                                     \
        }                                                                      \
    }

    f32x4 acc[8][4];
#pragma unroll
    for (int i = 0; i < 8; ++i)
#pragma unroll
        for (int g = 0; g < 4; ++g) { f32x4 zz = {0.f,0.f,0.f,0.f}; acc[i][g] = zz; }

#pragma unroll
    for (int u = 0; u < 6; ++u) STAGE8(u);
    asm volatile("s_waitcnt vmcnt(4)" ::: "memory");
    __builtin_amdgcn_sched_barrier(0);
    __builtin_amdgcn_s_barrier();

    const int iters = NT >> 1;
    for (int it = 0; it < iters; ++it) {
#pragma unroll
        for (int p = 0; p < 8; ++p) {
            STAGE8(it * 8 + p + 6);
            const int d  = p >> 2;
            const int mh = p & 1, kh = (p >> 1) & 1;
            short8 af[4], bfr[4];
#pragma unroll
            for (int f = 0; f < 4; ++f) {
                const int row = wr * 128 + (mh * 4 + f) * 16 + fr;
                const int ch = lg ^ ((row >> 1) & 3);
                af[f] = *(const short8*)(&L[d][kh * 2][row * 32 + ch * 8]);
            }
#pragma unroll
            for (int g = 0; g < 4; ++g) {
                const int row = wc * 64 + g * 16 + fr;
                const int ch = lg ^ ((row >> 1) & 3);
                bfr[g] = *(const short8*)(&L[d][kh * 2 + 1][row * 32 + ch * 8]);
            }
            __builtin_amdgcn_s_barrier();
            __builtin_amdgcn_s_setprio(1);
#pragma unroll
            for (int f = 0; f < 4; ++f)
#pragma unroll
                for (int g = 0; g < 4; ++g)
                    acc[mh * 4 + f][g] = __builtin_amdgcn_mfma_f32_16x16x32_bf16(
                        af[f], bfr[g], acc[mh * 4 + f][g], 0, 0, 0);
            __builtin_amdgcn_s_setprio(0);
            if (p == 3 || p == 7) {
                asm volatile("s_waitcnt vmcnt(4)" ::: "memory");
                __builtin_amdgcn_sched_barrier(0);
            }
            __builtin_amdgcn_s_barrier();
        }
    }

#pragma unroll
    for (int mi = 0; mi < 8; ++mi) {
#pragma unroll
        for (int g = 0; g < 4; ++g) {
            const int col = bcol + wc * 64 + g * 16 + fr;
            const float bv = bias[col];
#pragma unroll
            for (int r = 0; r < 4; ++r) {
                const int row = brow + wr * 128 + mi * 16 + lg * 4 + r;
                const float v = fmaxf(acc[mi][g][r] + bv, 0.f);
                C[(size_t)row * N + col] = f2bf(v);
            }
        }
    }
#undef STAGE8
}

// ---------------------------------------------------------------------------
// 4-phase 256x128 bf16 MFMA GEMM, split-K partials (proj & ffn2).
// Phase = (dbuf, k-half): 8 A-frags + 2 B-frags, 16 MFMA per barrier-pair;
// 2 STG units/phase keeps the stage stream identical to the 8-phase version
// (counted vmcnt(3) invariant unchanged). Per-acc k-order identical.
// ---------------------------------------------------------------------------
#define SOFF(slot) ((slot) == 0 ? 0 : (slot) == 1 ? 8192 : (slot) == 2 ? 12288 : 20480)

template <int KSPLIT>
__global__ __launch_bounds__(512, 2) void gemm8p_n128(
    const ushort_t* __restrict__ A, const ushort_t* __restrict__ Bt,
    ushort_t* __restrict__ C, int M, int N, int K)
{
    __shared__ __align__(16) ushort_t L[2][24576];  // 96 KiB

    const int tid = threadIdx.x;
    const int w = tid >> 6, l = tid & 63;
    const int fr = l & 15, lg = l >> 4;
    const int wr = w >> 2, wc = w & 3;

    const int z = blockIdx.z;
    const int Keff = K / KSPLIT;
    const int kb = z * Keff;

    const int gx = gridDim.x;
    const int nwg = gx * gridDim.y;
    const int bid = blockIdx.y * gx + blockIdx.x;
    int tile = bid;
    if ((nwg & 7) == 0) tile = (bid & 7) * (nwg >> 3) + (bid >> 3);
    const int bx = tile % gx, by = tile / gx;
    const int brow = by * 256, bcol = bx * 128;

    const int NT = Keff >> 6;
    const int UMAX = NT << 2;

#define STG(u)                                                                 \
    if ((u) < UMAX) {                                                          \
        const int tt = (u) >> 2, slot = (u) & 3;                               \
        const int op = slot & 1, kh = slot >> 1;                               \
        const ushort_t* sp = op ? Bt : A;                                      \
        const int rb = op ? bcol : brow;                                       \
        ushort_t* db = (ushort_t*)L[tt & 1] + SOFF(slot);                      \
        const int nld = op ? 1 : 2;                                            \
        _Pragma("unroll")                                                      \
        for (int j = 0; j < nld; ++j) {                                        \
            const int id = j * 512 + tid;                                      \
            const int row = id >> 2, c = id & 3;                               \
            const int cs = c ^ ((row >> 1) & 3);                               \
            gload16(sp + (size_t)(rb + row) * K + kb + tt * 64 + kh * 32 + cs * 8, \
                    (void*)(db + id * 8));                                     \
        }                                                                      \
    }

    f32x4 acc[8][2];
#pragma unroll
    for (int i = 0; i < 8; ++i)
#pragma unroll
        for (int g = 0; g < 2; ++g) { f32x4 zz = {0.f,0.f,0.f,0.f}; acc[i][g] = zz; }

#pragma unroll
    for (int u = 0; u < 6; ++u) STG(u);
    asm volatile("s_waitcnt vmcnt(3)" ::: "memory");
    __builtin_amdgcn_sched_barrier(0);
    __builtin_amdgcn_s_barrier();

    const int iters = NT >> 1;
    for (int it = 0; it < iters; ++it) {
#pragma unroll
        for (int p = 0; p < 4; ++p) {
            STG(it * 8 + 2 * p + 6);
            STG(it * 8 + 2 * p + 7);
            const int d  = p >> 1;
            const int kh = p & 1;
            short8 af[8], bfr[2];
#pragma unroll
            for (int f = 0; f < 8; ++f) {
                const int row = wr * 128 + f * 16 + fr;
                const int ch = lg ^ ((row >> 1) & 3);
                af[f] = *(const short8*)(&L[d][SOFF(kh * 2) + row * 32 + ch * 8]);
            }
#pragma unroll
            for (int g = 0; g < 2; ++g) {
                const int row = wc * 32 + g * 16 + fr;
                const int ch = lg ^ ((row >> 1) & 3);
                bfr[g] = *(const short8*)(&L[d][SOFF(kh * 2 + 1) + row * 32 + ch * 8]);
            }
            __builtin_amdgcn_s_barrier();
            __builtin_amdgcn_s_setprio(1);
#pragma unroll
            for (int f = 0; f < 8; ++f)
#pragma unroll
                for (int g = 0; g < 2; ++g)
                    acc[f][g] = __builtin_amdgcn_mfma_f32_16x16x32_bf16(
                        af[f], bfr[g], acc[f][g], 0, 0, 0);
            __builtin_amdgcn_s_setprio(0);
            if (p == 1 || p == 3) {
                asm volatile("s_waitcnt vmcnt(3)" ::: "memory");
                __builtin_amdgcn_sched_barrier(0);
            }
            __builtin_amdgcn_s_barrier();
        }
    }

    ushort_t* Cb = C + (size_t)z * M * N;
#pragma unroll
    for (int mi = 0; mi < 8; ++mi) {
#pragma unroll
        for (int g = 0; g < 2; ++g) {
            const int col = bcol + wc * 32 + g * 16 + fr;
#pragma unroll
            for (int r = 0; r < 4; ++r) {
                const int row = brow + wr * 128 + mi * 16 + lg * 4 + r;
                Cb[(size_t)row * N + col] = f2bf(acc[mi][g][r]);
            }
        }
    }
#undef STG
}

// ---------------------------------------------------------------------------
// LN1: x = LN(p0 + p1 + b_out + query), p bf16 / query f32; bf16 out.
// ---------------------------------------------------------------------------
__global__ __launch_bounds__(256) void ln_mid(
    const ushort_t* __restrict__ y0, const ushort_t* __restrict__ y1,
    const float* __restrict__ qres, const float* __restrict__ b0,
    const float* __restrict__ g, const float* __restrict__ b,
    ushort_t* __restrict__ out)
{
    const int row = blockIdx.x;
    const int t = threadIdx.x;
    const size_t off = (size_t)row * EE;
    const uint2 a = ((const uint2*)(y0 + off))[t];
    const uint2 c = ((const uint2*)(y1 + off))[t];
    const float4 qq = ((const float4*)(qres + off))[t];
    const float4 b04 = ((const float4*)b0)[t];
    float x[4];
    x[0] = bf2f(a.x & 0xffff) + bf2f(c.x & 0xffff) + qq.x + b04.x;
    x[1] = bf2f(a.x >> 16)    + bf2f(c.x >> 16)    + qq.y + b04.y;
    x[2] = bf2f(a.y & 0xffff) + bf2f(c.y & 0xffff) + qq.z + b04.z;
    x[3] = bf2f(a.y >> 16)    + bf2f(c.y >> 16)    + qq.w + b04.w;

    float s = 0.f, ss = 0.f;
#pragma unroll
    for (int i = 0; i < 4; ++i) { s += x[i]; ss += x[i] * x[i]; }
#pragma unroll
    for (int o = 1; o < 64; o <<= 1) {
        s  += __shfl_xor(s, o, 64);
        ss += __shfl_xor(ss, o, 64);
    }
    __shared__ float sm[8];
    const int wid = t >> 6;
    if ((t & 63) == 0) { sm[wid * 2] = s; sm[wid * 2 + 1] = ss; }
    __syncthreads();
    const float stot  = sm[0] + sm[2] + sm[4] + sm[6];
    const float sstot = sm[1] + sm[3] + sm[5] + sm[7];
    const float mu  = stot * (1.f / EE);
    const float inv = rsqrtf(sstot * (1.f / EE) - mu * mu + LN_EPS);

    const float4 gg = ((const float4*)g)[t];
    const float4 bb = ((const float4*)b)[t];
    uint2 pk;
    pk.x = f2bf((x[0] - mu) * inv * gg.x + bb.x) |
           ((unsigned)f2bf((x[1] - mu) * inv * gg.y + bb.y) << 16);
    pk.y = f2bf((x[2] - mu) * inv * gg.z + bb.z) |
           ((unsigned)f2bf((x[3] - mu) * inv * gg.w + bb.w) << 16);
    ((uint2*)(out + off))[t] = pk;
}

// ---------------------------------------------------------------------------
// LN2: out = LN(y0 + y1 + b2 + x), all-bf16 inputs, f32 out.
// ---------------------------------------------------------------------------
__global__ __launch_bounds__(256) void ln_out(
    const ushort_t* __restrict__ y0, const ushort_t* __restrict__ y1,
    const ushort_t* __restrict__ xb, const float* __restrict__ b2,
    const float* __restrict__ g, const float* __restrict__ be,
    float* __restrict__ out)
{
    const int row = blockIdx.x;
    const int t = threadIdx.x;
    const size_t off = (size_t)row * EE;
    const uint2 a = ((const uint2*)(y0 + off))[t];
    const uint2 b = ((const uint2*)(y1 + off))[t];
    const uint2 c = ((const uint2*)(xb + off))[t];
    const float4 bb2 = ((const float4*)b2)[t];
    float x[4];
    x[0] = bf2f(a.x & 0xffff) + bf2f(b.x & 0xffff) + bf2f(c.x & 0xffff) + bb2.x;
    x[1] = bf2f(a.x >> 16)    + bf2f(b.x >> 16)    + bf2f(c.x >> 16)    + bb2.y;
    x[2] = bf2f(a.y & 0xffff) + bf2f(b.y & 0xffff) + bf2f(c.y & 0xffff) + bb2.z;
    x[3] = bf2f(a.y >> 16)    + bf2f(b.y >> 16)    + bf2f(c.y >> 16)    + bb2.w;

    float s = 0.f, ss = 0.f;
#pragma unroll
    for (int i = 0; i < 4; ++i) { s += x[i]; ss += x[i] * x[i]; }
#pragma unroll
    for (int o = 1; o < 64; o <<= 1) {
        s  += __shfl_xor(s, o, 64);
        ss += __shfl_xor(ss, o, 64);
    }
    __shared__ float sm[8];
    const int wid = t >> 6;
    if ((t & 63) == 0) { sm[wid * 2] = s; sm[wid * 2 + 1] = ss; }
    __syncthreads();
    const float stot  = sm[0] + sm[2] + sm[4] + sm[6];
    const float sstot = sm[1] + sm[3] + sm[5] + sm[7];
    const float mu  = stot * (1.f / EE);
    const float inv = rsqrtf(sstot * (1.f / EE) - mu * mu + LN_EPS);

    const float4 gg = ((const float4*)g)[t];
    const float4 bb = ((const float4*)be)[t];
    float4 o;
    o.x = (x[0] - mu) * inv * gg.x + bb.x;
    o.y = (x[1] - mu) * inv * gg.y + bb.y;
    o.z = (x[2] - mu) * inv * gg.z + bb.z;
    o.w = (x[3] - mu) * inv * gg.w + bb.w;
    ((float4*)(out + off))[t] = o;
}

// ---------------------------------------------------------------------------
extern "C" void kernel_launch(void* const* d_in, const int* in_sizes, int n_in,
                              void* d_out, int out_size, void* d_ws, size_t ws_size,
                              hipStream_t stream) {
    (void)in_sizes; (void)n_in; (void)out_size; (void)ws_size;
    const float* value = (const float*)d_in[0];
    const float* key   = (const float*)d_in[1];
    const float* query = (const float*)d_in[2];
    const float* w_out = (const float*)d_in[3];
    const float* b_out = (const float*)d_in[4];
    const float* w1    = (const float*)d_in[5];
    const float* b1    = (const float*)d_in[6];
    const float* w2    = (const float*)d_in[7];
    const float* b2    = (const float*)d_in[8];
    const float* g1    = (const float*)d_in[9];
    const float* be1   = (const float*)d_in[10];
    const float* g2    = (const float*)d_in[11];
    const float* be2   = (const float*)d_in[12];
    float* out = (float*)d_out;

    const int M = NB * LL;  // 4096
    char* base = (char*)d_ws;
    ushort_t* attn_bf = (ushort_t*)(base);                      //  8 MB
    ushort_t* x_bf    = (ushort_t*)(base + (8ull  << 20));      //  8 MB
    char*     hregion = base + (16ull << 20);                   // 32 MB
    ushort_t* h_bf    = (ushort_t*)hregion;                     //  (post-attn)
    ushort_t* Kh      = (ushort_t*)(hregion);                   //  8 MB (pre-attn)
    ushort_t* Vt      = (ushort_t*)(hregion + (8ull  << 20));   //  8 MB
    ushort_t* y01     = (ushort_t*)(base + (48ull << 20));      // 16 MB (2 partials)
    ushort_t* w0T     = (ushort_t*)(base + (64ull << 20));      //  2 MB
    ushort_t* w1T     = (ushort_t*)(base + (66ull << 20));      //  8 MB
    ushort_t* w2T     = (ushort_t*)(base + (74ull << 20));      //  8 MB (ends 82)

    prep<<<12288, 256, 0, stream>>>(w_out, w1, w2, key, value,
                                    w0T, w1T, w2T, Kh, Vt);

    attn_mfma<<<dim3(NB * HH * LL / 64), 256, 0, stream>>>(query, Kh, Vt,
                                                           attn_bf);

    // proj: split-K=2 partials (4-phase 256x128), bias+residual fused in LN1
    gemm8p_n128<2><<<dim3(EE / 128, M / 256, 2), 512, 0, stream>>>(
        attn_bf, w0T, y01, M, EE, EE);
    ln_mid<<<M, 256, 0, stream>>>(y01, y01 + (size_t)M * EE, query, b_out,
                                  g1, be1, x_bf);

    // ffn1: [4096,4096] = relu(x_bf @ w1T + b1), bf16 out (8-phase 256x256)
    gemm8p<<<dim3(FFD / 256, M / 256), 512, 0, stream>>>(x_bf, w1T, b1, h_bf,
                                                         M, FFD, EE);
    // ffn2: split-K=2 partials (4-phase 256x128)
    gemm8p_n128<2><<<dim3(EE / 128, M / 256, 2), 512, 0, stream>>>(
        h_bf, w2T, y01, M, EE, FFD);
    ln_out<<<M, 256, 0, stream>>>(y01, y01 + (size_t)M * EE, x_bf, b2, g2, be2,
                                  out);
}